// Round 2
// baseline (5952.833 us; speedup 1.0000x reference)
//
#include <hip/hip_runtime.h>

// ---------------------------------------------------------------------------
// FCGRU (all global tensors fp32; bf16 only inside MFMA fragments):
//   input(1024,128,32) -> FC(32->256) -> FC(256->512) -> GRU(512) over T=128
//   -> relu -> FC(512->256)+relu -> per-cultivar head (256->16)
// Input-side linears collapse: gx = input @ (W_ih@W2@W1).T + b_eff  (K=32 MFMA).
// Persistent GRU: 8 groups x 32 blocks, per-group device barrier, W_hh slice in
// LDS (bf16), h double-buffered bf16 in ws, carried h-state fp32 in registers.
// ---------------------------------------------------------------------------

#define T_STEPS 128

typedef __attribute__((ext_vector_type(8))) short short8;
typedef __attribute__((ext_vector_type(4))) float f32x4;
typedef unsigned short u16;

static __device__ __forceinline__ u16 f2bf(float f) {
    unsigned int u = __builtin_bit_cast(unsigned int, f);
    u += 0x7FFFu + ((u >> 16) & 1u);          // round-to-nearest-even
    return (u16)(u >> 16);
}
static __device__ __forceinline__ float bf2f(u16 u) {
    unsigned int v = ((unsigned int)u) << 16;
    return __builtin_bit_cast(float, v);
}
static __device__ __forceinline__ f32x4 mfma16(short8 a, short8 b, f32x4 c) {
    return __builtin_amdgcn_mfma_f32_16x16x32_bf16(a, b, c, 0, 0, 0);
}

// ---------------- workspace layout (bytes) ----------------
#define WS_HBUF0 0           // 1024*512*2  = 1048576  (bf16 h, buffer 0)
#define WS_HBUF1 1048576     // 1024*512*2             (bf16 h, buffer 1)
#define WS_W21   2097152     // 512*32*4    = 65536    (fp32 W2@W1)
#define WS_B21   2162688     // 512*4
#define WS_WEFF  2164736     // 1536*32*2   = 98304    (bf16 W_ih@W2@W1)
#define WS_BEFF  2263040     // 1536*4
#define WS_CTRS  2269184     // 8 counters, 64B apart

// ---------------- prologue 0: W21 = W2@W1 (fp32); b21 = W2@b1 + b2; zero ctrs
__global__ void k_prep0(const float* __restrict__ W1, const float* __restrict__ b1,
                        const float* __restrict__ W2, const float* __restrict__ b2,
                        float* __restrict__ W21, float* __restrict__ b21,
                        unsigned* __restrict__ ctrs) {
    if (blockIdx.x == 0 && threadIdx.x < 8) ctrs[threadIdx.x * 16] = 0u;
    int gid = blockIdx.x * 256 + threadIdx.x;   // 64 blocks: 512*32 outputs
    int k = gid >> 5, d = gid & 31;
    float acc = 0.f;
    for (int j = 0; j < 256; ++j)
        acc += W2[k * 256 + j] * W1[j * 32 + d];
    W21[k * 32 + d] = acc;
    if (d == 0) {
        float bb = b2[k];
        for (int j = 0; j < 256; ++j) bb += W2[k * 256 + j] * b1[j];
        b21[k] = bb;
    }
}

// ---------------- prologue 1: Weff = bf16(W_ih@W21); beff = W_ih@b21 + b_ih
__global__ void k_prep1(const float* __restrict__ W_ih, const float* __restrict__ b_ih,
                        const float* __restrict__ W21, const float* __restrict__ b21,
                        u16* __restrict__ Weff, float* __restrict__ beff) {
    int gid = blockIdx.x * 256 + threadIdx.x;   // 192 blocks: 1536*32 outputs
    int g = gid >> 5, d = gid & 31;
    float acc = 0.f;
    for (int k = 0; k < 512; ++k)
        acc += W_ih[g * 512 + k] * W21[k * 32 + d];
    Weff[g * 32 + d] = f2bf(acc);
    if (d == 0) {
        float bb = b_ih[g];
        for (int k = 0; k < 512; ++k) bb += W_ih[g * 512 + k] * b21[k];
        beff[g] = bb;
    }
}

// ---------------- per-group barrier (device-scope; grid <= 256 CUs co-resident)
static __device__ __forceinline__ void group_bar(unsigned* ctr, unsigned target) {
    __threadfence();                 // release: flush h stores device-wide
    __syncthreads();
    if (threadIdx.x == 0) {
        __hip_atomic_fetch_add(ctr, 1u, __ATOMIC_RELAXED, __HIP_MEMORY_SCOPE_AGENT);
        while (__hip_atomic_load(ctr, __ATOMIC_RELAXED, __HIP_MEMORY_SCOPE_AGENT) < target)
            __builtin_amdgcn_s_sleep(2);
    }
    __syncthreads();
    __threadfence();                 // acquire: invalidate stale caches
}

// ---------------- GRU persistent kernel ----------------
// grid 256 x 256. group = blk&7 (128 batches), colgroup = blk>>3 (16 h-cols).
__launch_bounds__(256, 1)
__global__ void k_gru(const float* __restrict__ input, const float* __restrict__ hn,
                      const float* __restrict__ W_hh, const float* __restrict__ b_hh,
                      const u16* __restrict__ Weff, const float* __restrict__ beff,
                      u16* __restrict__ hbuf0, u16* __restrict__ hbuf1,
                      unsigned* __restrict__ ctrs, float* __restrict__ hn_out) {
    __shared__ __align__(16) u16 whh[48][520];   // 48 rows x 512 bf16, +8 pad

    const int tid  = threadIdx.x;
    const int wave = tid >> 6, lane = tid & 63;
    const int col_l = lane & 15, quad = lane >> 4;
    const int blk = blockIdx.x;
    const int grp = blk & 7, colg = blk >> 3;
    const int colbase = colg * 16;
    const int bbase = grp * 128 + wave * 32;
    unsigned* ctr = ctrs + grp * 16;

    // stage this block's 48 W_hh rows (r,z,n x 16 cols), fp32 -> bf16 LDS
    for (int idx = tid; idx < 48 * 64; idx += 256) {
        int r = idx >> 6, ch = idx & 63;
        int g3 = r >> 4, c = r & 15;
        const float* src = W_hh + (size_t)(g3 * 512 + colbase + c) * 512 + ch * 8;
        short8 v;
        #pragma unroll
        for (int e = 0; e < 8; ++e) v[e] = (short)f2bf(src[e]);
        *(short8*)(&whh[r][ch * 8]) = v;
    }
    // copy this block's 4 batches of hn -> hbuf0 (bf16)
    {
        int b = grp * 128 + colg * 4 + wave;     // 1 row per wave
        const float* src = hn + (size_t)b * 512 + lane * 8;
        short8 v;
        #pragma unroll
        for (int e = 0; e < 8; ++e) v[e] = (short)f2bf(src[e]);
        *(short8*)(hbuf0 + (size_t)b * 512 + lane * 8) = v;
    }
    // register-resident W_eff B-frags (bf16) + per-column biases (fp32)
    short8 bwx[3];
    float bx[3], bhh[3];
    #pragma unroll
    for (int g3 = 0; g3 < 3; ++g3) {
        int nrow = g3 * 512 + colbase + col_l;
        bwx[g3] = *(const short8*)(Weff + nrow * 32 + quad * 8);
        bx[g3]  = beff[nrow];
        bhh[g3] = b_hh[nrow];
    }
    // fp32 carried h-state, C-tile layout: batch = bbase + s*16 + quad*4 + i
    float hs[2][4];
    #pragma unroll
    for (int s = 0; s < 2; ++s)
        #pragma unroll
        for (int i = 0; i < 4; ++i)
            hs[s][i] = hn[(size_t)(bbase + s * 16 + quad * 4 + i) * 512 + colbase + col_l];

    group_bar(ctr, 32u);                          // hn copy visible group-wide

    u16* bufs[2] = { hbuf0, hbuf1 };
    #pragma unroll 1
    for (int t = 0; t < T_STEPS; ++t) {
        const u16* hsrc = bufs[t & 1];
        u16* hdst = bufs[(t + 1) & 1];

        f32x4 ar[2], az[2], anx[2], anh[2];
        // gx seed: K=32 MFMA on the fly (input fp32 -> bf16 frag)
        #pragma unroll
        for (int s = 0; s < 2; ++s) {
            const float* xp = input + (size_t)(bbase + s * 16 + col_l) * 4096 + t * 32 + quad * 8;
            short8 ax;
            #pragma unroll
            for (int e = 0; e < 8; ++e) ax[e] = (short)f2bf(xp[e]);
            f32x4 z4 = { 0.f, 0.f, 0.f, 0.f };
            ar[s]  = mfma16(ax, bwx[0], z4);
            az[s]  = mfma16(ax, bwx[1], z4);
            anx[s] = mfma16(ax, bwx[2], z4);
            anh[s] = z4;
        }
        // gh: K=512 over bf16 h (A from global hbuf, B from LDS)
        #pragma unroll
        for (int kc = 0; kc < 16; ++kc) {
            short8 a0 = *(const short8*)(hsrc + (size_t)(bbase + col_l) * 512 + kc * 32 + quad * 8);
            short8 a1 = *(const short8*)(hsrc + (size_t)(bbase + 16 + col_l) * 512 + kc * 32 + quad * 8);
            short8 br = *(const short8*)(&whh[ 0 + col_l][kc * 32 + quad * 8]);
            short8 bz = *(const short8*)(&whh[16 + col_l][kc * 32 + quad * 8]);
            short8 bn = *(const short8*)(&whh[32 + col_l][kc * 32 + quad * 8]);
            ar[0]  = mfma16(a0, br, ar[0]);   ar[1]  = mfma16(a1, br, ar[1]);
            az[0]  = mfma16(a0, bz, az[0]);   az[1]  = mfma16(a1, bz, az[1]);
            anh[0] = mfma16(a0, bn, anh[0]);  anh[1] = mfma16(a1, bn, anh[1]);
        }
        // gates + state update (fp32), store bf16 h_new
        #pragma unroll
        for (int s = 0; s < 2; ++s) {
            #pragma unroll
            for (int i = 0; i < 4; ++i) {
                float r = 1.f / (1.f + __expf(-(ar[s][i] + bx[0] + bhh[0])));
                float z = 1.f / (1.f + __expf(-(az[s][i] + bx[1] + bhh[1])));
                float np = anx[s][i] + bx[2] + r * (anh[s][i] + bhh[2]);
                float e  = __expf(-2.f * fabsf(np));
                float nn = __builtin_copysignf((1.f - e) / (1.f + e), np);
                float h  = (1.f - z) * nn + z * hs[s][i];
                hs[s][i] = h;
                hdst[(size_t)(bbase + s * 16 + quad * 4 + i) * 512 + colbase + col_l] = f2bf(h);
            }
        }
        group_bar(ctr, 32u * (t + 2));
    }
    // final hidden state -> d_out hn region (fp32)
    #pragma unroll
    for (int s = 0; s < 2; ++s)
        #pragma unroll
        for (int i = 0; i < 4; ++i)
            hn_out[(size_t)(bbase + s * 16 + quad * 4 + i) * 512 + colbase + col_l] = hs[s][i];
}

// ---------------- epilogue: out2 = relu(relu(h)@W3.T + b3); params = out2.Wh[cult] + bh
// hfin = bf16 final h (hbuf0: step 127 wrote buffer (127+1)&1 = 0)
__launch_bounds__(256)
__global__ void k_head(const u16* __restrict__ hfin, const float* __restrict__ W3,
                       const float* __restrict__ b3, const int* __restrict__ cult,
                       const float* __restrict__ Wh, const float* __restrict__ bh,
                       float* __restrict__ params) {
    __shared__ float out2[16][264];
    const int tid = threadIdx.x, wave = tid >> 6, lane = tid & 63;
    const int col_l = lane & 15, quad = lane >> 4;
    const int bbase = blockIdx.x * 16;            // 64 blocks x 16 batches

    f32x4 z4 = { 0.f, 0.f, 0.f, 0.f };
    f32x4 acc[4];
    #pragma unroll
    for (int nt = 0; nt < 4; ++nt) acc[nt] = z4;

    #pragma unroll
    for (int kc = 0; kc < 16; ++kc) {
        short8 a = *(const short8*)(hfin + (size_t)(bbase + col_l) * 512 + kc * 32 + quad * 8);
        #pragma unroll
        for (int e = 0; e < 8; ++e) {             // relu on packed bf16 (sign test)
            u16 v = (u16)a[e];
            a[e] = (short)((v & 0x8000u) ? 0 : v);
        }
        #pragma unroll
        for (int nt = 0; nt < 4; ++nt) {
            int nrow = wave * 64 + nt * 16 + col_l;
            const float* wr = W3 + (size_t)nrow * 512 + kc * 32 + quad * 8;
            short8 b;
            #pragma unroll
            for (int e = 0; e < 8; ++e) b[e] = (short)f2bf(wr[e]);
            acc[nt] = mfma16(a, b, acc[nt]);
        }
    }
    #pragma unroll
    for (int nt = 0; nt < 4; ++nt) {
        int ncol = wave * 64 + nt * 16 + col_l;
        float bias = b3[ncol];
        #pragma unroll
        for (int i = 0; i < 4; ++i) {
            float v = acc[nt][i] + bias;
            out2[quad * 4 + i][ncol] = v > 0.f ? v : 0.f;
        }
    }
    __syncthreads();
    // per-cultivar head: 16 batches x 16 outputs = 256 threads, 256-MAC dot each
    int b_local = tid >> 4, o2 = tid & 15;
    int batch = bbase + b_local;
    int c = cult[batch];
    float acc2 = bh[c * 16 + o2];
    const float* wrow = Wh + (size_t)(c * 16 + o2) * 256;
    for (int d = 0; d < 256; ++d) acc2 += out2[b_local][d] * wrow[d];
    params[(size_t)batch * 16 + o2] = acc2;
}

// ---------------- launcher ----------------
extern "C" void kernel_launch(void* const* d_in, const int* in_sizes, int n_in,
                              void* d_out, int out_size, void* d_ws, size_t ws_size,
                              hipStream_t stream) {
    (void)in_sizes; (void)n_in; (void)out_size; (void)ws_size;
    const float* input = (const float*)d_in[0];
    const float* hn    = (const float*)d_in[1];
    const int*   cult  = (const int*)d_in[2];
    const float* W1    = (const float*)d_in[3];
    const float* b1    = (const float*)d_in[4];
    const float* W2    = (const float*)d_in[5];
    const float* b2    = (const float*)d_in[6];
    const float* W_ih  = (const float*)d_in[7];
    const float* W_hh  = (const float*)d_in[8];
    const float* b_ih  = (const float*)d_in[9];
    const float* b_hh  = (const float*)d_in[10];
    const float* W3    = (const float*)d_in[11];
    const float* b3    = (const float*)d_in[12];
    const float* Wh    = (const float*)d_in[13];
    const float* bh    = (const float*)d_in[14];

    char* ws = (char*)d_ws;
    u16*      hbuf0 = (u16*)(ws + WS_HBUF0);
    u16*      hbuf1 = (u16*)(ws + WS_HBUF1);
    float*    W21   = (float*)(ws + WS_W21);
    float*    b21   = (float*)(ws + WS_B21);
    u16*      Weff  = (u16*)(ws + WS_WEFF);
    float*    beff  = (float*)(ws + WS_BEFF);
    unsigned* ctrs  = (unsigned*)(ws + WS_CTRS);

    float* out    = (float*)d_out;
    float* params = out;            // 1024*16 fp32
    float* hnout  = out + 16384;    // 1024*512 fp32

    k_prep0<<<64, 256, 0, stream>>>(W1, b1, W2, b2, W21, b21, ctrs);
    k_prep1<<<192, 256, 0, stream>>>(W_ih, b_ih, W21, b21, Weff, beff);
    k_gru<<<256, 256, 0, stream>>>(input, hn, W_hh, b_hh, Weff, beff,
                                   hbuf0, hbuf1, ctrs, hnout);
    k_head<<<64, 256, 0, stream>>>(hbuf0, W3, b3, cult, Wh, bh, params);
}

// Round 3
// 1531.315 us; speedup vs baseline: 3.8874x; 3.8874x over previous
//
#include <hip/hip_runtime.h>

// ---------------------------------------------------------------------------
// FCGRU (fp32 globals; bf16 in MFMA frags):
//   input(1024,128,32) -> FC(32->256) -> FC(256->512) -> GRU(512) over T=128
//   -> relu -> FC(512->256)+relu -> per-cultivar head (256->16)
// Input-side linears collapse: gx = input @ (W_ih@W2@W1).T + b_eff  (K=32 MFMA).
// Persistent GRU: 8 groups x 32 blocks; cross-block h exchange uses RELAXED
// AGENT-scope atomics (sc1: coherent at MALL, no L2 wb/inv!). Barrier is
// fence-free: sc1 stores + __syncthreads (drains vmcnt) + relaxed atomic ctr.
// W_hh slice lives in LDS; carried h-state fp32 in registers.
// ---------------------------------------------------------------------------

#define T_STEPS 128

typedef __attribute__((ext_vector_type(8))) short short8;
typedef __attribute__((ext_vector_type(4))) float f32x4;
typedef unsigned short u16;
typedef unsigned long long u64;

static __device__ __forceinline__ u16 f2bf(float f) {
    unsigned int u = __builtin_bit_cast(unsigned int, f);
    u += 0x7FFFu + ((u >> 16) & 1u);          // round-to-nearest-even
    return (u16)(u >> 16);
}
static __device__ __forceinline__ f32x4 mfma16(short8 a, short8 b, f32x4 c) {
    return __builtin_amdgcn_mfma_f32_16x16x32_bf16(a, b, c, 0, 0, 0);
}
// 16B device-coherent load/store of h (2x u64 relaxed agent atomics -> sc1)
static __device__ __forceinline__ short8 ld_h16(const u16* p) {
    const u64* q = (const u64*)p;
    u64 lo = __hip_atomic_load(q + 0, __ATOMIC_RELAXED, __HIP_MEMORY_SCOPE_AGENT);
    u64 hi = __hip_atomic_load(q + 1, __ATOMIC_RELAXED, __HIP_MEMORY_SCOPE_AGENT);
    struct { u64 a, b; } w{lo, hi};
    return __builtin_bit_cast(short8, w);
}
static __device__ __forceinline__ void st_h16(u16* p, short8 v) {
    struct W { u64 a, b; } w = __builtin_bit_cast(W, v);
    u64* q = (u64*)p;
    __hip_atomic_store(q + 0, w.a, __ATOMIC_RELAXED, __HIP_MEMORY_SCOPE_AGENT);
    __hip_atomic_store(q + 1, w.b, __ATOMIC_RELAXED, __HIP_MEMORY_SCOPE_AGENT);
}

// ---------------- workspace layout (bytes) ----------------
#define WS_HBUF0 0           // 1024*512*2 bf16 h buffer 0
#define WS_HBUF1 1048576     // 1024*512*2 bf16 h buffer 1
#define WS_W21   2097152     // 512*32*4 fp32 W2@W1
#define WS_B21   2162688     // 512*4
#define WS_WEFF  2164736     // 1536*32*2 bf16 W_ih@W2@W1
#define WS_BEFF  2263040     // 1536*4
#define WS_CTRS  2269184     // 8 counters, 64B apart

// ---------------- prologue 0: W21 = W2@W1 (fp32); b21 = W2@b1 + b2; zero ctrs
__global__ void k_prep0(const float* __restrict__ W1, const float* __restrict__ b1,
                        const float* __restrict__ W2, const float* __restrict__ b2,
                        float* __restrict__ W21, float* __restrict__ b21,
                        unsigned* __restrict__ ctrs) {
    if (blockIdx.x == 0 && threadIdx.x < 8)
        __hip_atomic_store(&ctrs[threadIdx.x * 16], 0u, __ATOMIC_RELAXED, __HIP_MEMORY_SCOPE_AGENT);
    int gid = blockIdx.x * 256 + threadIdx.x;   // 64 blocks: 512*32 outputs
    int k = gid >> 5, d = gid & 31;
    float acc = 0.f;
    for (int j = 0; j < 256; ++j)
        acc += W2[k * 256 + j] * W1[j * 32 + d];
    W21[k * 32 + d] = acc;
    if (d == 0) {
        float bb = b2[k];
        for (int j = 0; j < 256; ++j) bb += W2[k * 256 + j] * b1[j];
        b21[k] = bb;
    }
}

// ---------------- prologue 1: Weff = bf16(W_ih@W21); beff = W_ih@b21 + b_ih
__global__ void k_prep1(const float* __restrict__ W_ih, const float* __restrict__ b_ih,
                        const float* __restrict__ W21, const float* __restrict__ b21,
                        u16* __restrict__ Weff, float* __restrict__ beff) {
    int gid = blockIdx.x * 256 + threadIdx.x;   // 192 blocks: 1536*32 outputs
    int g = gid >> 5, d = gid & 31;
    float acc = 0.f;
    for (int k = 0; k < 512; ++k)
        acc += W_ih[g * 512 + k] * W21[k * 32 + d];
    Weff[g * 32 + d] = f2bf(acc);
    if (d == 0) {
        float bb = b_ih[g];
        for (int k = 0; k < 512; ++k) bb += W_ih[g * 512 + k] * b21[k];
        beff[g] = bb;
    }
}

// ---------------- fence-free group barrier ----------------
// Correctness: all cross-block data (hbuf) moves via sc1 (agent-scope relaxed
// atomics) which are coherent at MALL and never cached in L1/L2. The
// __syncthreads() before the add drains vmcnt(0) for every wave in the block,
// so all sc1 stores are globally visible before the counter increment.
// Readers' sc1 loads after the barrier cannot see stale data. No threadfence
// (no buffer_wbl2 / buffer_inv) anywhere.
static __device__ __forceinline__ void group_bar(unsigned* ctr, unsigned target) {
    __syncthreads();
    if (threadIdx.x == 0) {
        __hip_atomic_fetch_add(ctr, 1u, __ATOMIC_RELAXED, __HIP_MEMORY_SCOPE_AGENT);
        while (__hip_atomic_load(ctr, __ATOMIC_RELAXED, __HIP_MEMORY_SCOPE_AGENT) < target)
            __builtin_amdgcn_s_sleep(1);
    }
    __syncthreads();
}

// ---------------- GRU persistent kernel ----------------
// grid 256 x 256. group = blk&7 (128 batches), colgroup = blk>>3 (16 h-cols).
__launch_bounds__(256, 1)
__global__ void k_gru(const float* __restrict__ input, const float* __restrict__ hn,
                      const float* __restrict__ W_hh, const float* __restrict__ b_hh,
                      const u16* __restrict__ Weff, const float* __restrict__ beff,
                      u16* __restrict__ hbuf0, u16* __restrict__ hbuf1,
                      unsigned* __restrict__ ctrs, float* __restrict__ hn_out) {
    __shared__ __align__(16) u16 whh[48][520];   // 48 rows x 512 bf16, +8 pad

    const int tid  = threadIdx.x;
    const int wave = tid >> 6, lane = tid & 63;
    const int col_l = lane & 15, quad = lane >> 4;
    const int blk = blockIdx.x;
    const int grp = blk & 7, colg = blk >> 3;
    const int colbase = colg * 16;
    const int bbase = grp * 128 + wave * 32;
    unsigned* ctr = ctrs + grp * 16;

    // stage this block's 48 W_hh rows (r,z,n x 16 cols), fp32 -> bf16 LDS
    for (int idx = tid; idx < 48 * 64; idx += 256) {
        int r = idx >> 6, ch = idx & 63;
        int g3 = r >> 4, c = r & 15;
        const float* src = W_hh + (size_t)(g3 * 512 + colbase + c) * 512 + ch * 8;
        short8 v;
        #pragma unroll
        for (int e = 0; e < 8; ++e) v[e] = (short)f2bf(src[e]);
        *(short8*)(&whh[r][ch * 8]) = v;
    }
    // copy this block's 4 batches of hn -> hbuf0 (bf16, sc1 stores)
    {
        int b = grp * 128 + colg * 4 + wave;     // 1 row per wave
        const float* src = hn + (size_t)b * 512 + lane * 8;
        short8 v;
        #pragma unroll
        for (int e = 0; e < 8; ++e) v[e] = (short)f2bf(src[e]);
        st_h16(hbuf0 + (size_t)b * 512 + lane * 8, v);
    }
    // register-resident W_eff B-frags (bf16) + per-column biases (fp32)
    short8 bwx[3];
    float bx[3], bhh[3];
    #pragma unroll
    for (int g3 = 0; g3 < 3; ++g3) {
        int nrow = g3 * 512 + colbase + col_l;
        bwx[g3] = *(const short8*)(Weff + nrow * 32 + quad * 8);
        bx[g3]  = beff[nrow];
        bhh[g3] = b_hh[nrow];
    }
    // fp32 carried h-state, C-tile layout: batch = bbase + s*16 + quad*4 + i
    float hs[2][4];
    #pragma unroll
    for (int s = 0; s < 2; ++s)
        #pragma unroll
        for (int i = 0; i < 4; ++i)
            hs[s][i] = hn[(size_t)(bbase + s * 16 + quad * 4 + i) * 512 + colbase + col_l];

    group_bar(ctr, 32u);                          // hn copy visible group-wide

    u16* bufs[2] = { hbuf0, hbuf1 };
    #pragma unroll 1
    for (int t = 0; t < T_STEPS; ++t) {
        const u16* hsrc = bufs[t & 1];
        u16* hdst = bufs[(t + 1) & 1];

        // prefetch the whole step's A-frags (sc1, pipelined; 128 VGPRs)
        short8 a0f[16], a1f[16];
        #pragma unroll
        for (int kc = 0; kc < 16; ++kc) {
            a0f[kc] = ld_h16(hsrc + (size_t)(bbase + col_l) * 512 + kc * 32 + quad * 8);
            a1f[kc] = ld_h16(hsrc + (size_t)(bbase + 16 + col_l) * 512 + kc * 32 + quad * 8);
        }

        f32x4 ar[2], az[2], anx[2], anh[2];
        // gx seed: K=32 MFMA on the fly (input fp32 -> bf16 frag, cached loads)
        #pragma unroll
        for (int s = 0; s < 2; ++s) {
            const float* xp = input + (size_t)(bbase + s * 16 + col_l) * 4096 + t * 32 + quad * 8;
            short8 ax;
            #pragma unroll
            for (int e = 0; e < 8; ++e) ax[e] = (short)f2bf(xp[e]);
            f32x4 z4 = { 0.f, 0.f, 0.f, 0.f };
            ar[s]  = mfma16(ax, bwx[0], z4);
            az[s]  = mfma16(ax, bwx[1], z4);
            anx[s] = mfma16(ax, bwx[2], z4);
            anh[s] = z4;
        }
        // gh: K=512 over bf16 h (A from registers, B from LDS)
        #pragma unroll
        for (int kc = 0; kc < 16; ++kc) {
            short8 br = *(const short8*)(&whh[ 0 + col_l][kc * 32 + quad * 8]);
            short8 bz = *(const short8*)(&whh[16 + col_l][kc * 32 + quad * 8]);
            short8 bn = *(const short8*)(&whh[32 + col_l][kc * 32 + quad * 8]);
            ar[0]  = mfma16(a0f[kc], br, ar[0]);   ar[1]  = mfma16(a1f[kc], br, ar[1]);
            az[0]  = mfma16(a0f[kc], bz, az[0]);   az[1]  = mfma16(a1f[kc], bz, az[1]);
            anh[0] = mfma16(a0f[kc], bn, anh[0]);  anh[1] = mfma16(a1f[kc], bn, anh[1]);
        }
        // gates + state update (fp32), store bf16 h_new (sc1 stores)
        #pragma unroll
        for (int s = 0; s < 2; ++s) {
            #pragma unroll
            for (int i = 0; i < 4; ++i) {
                float r = 1.f / (1.f + __expf(-(ar[s][i] + bx[0] + bhh[0])));
                float z = 1.f / (1.f + __expf(-(az[s][i] + bx[1] + bhh[1])));
                float np = anx[s][i] + bx[2] + r * (anh[s][i] + bhh[2]);
                float e  = __expf(-2.f * fabsf(np));
                float nn = __builtin_copysignf((1.f - e) / (1.f + e), np);
                float h  = (1.f - z) * nn + z * hs[s][i];
                hs[s][i] = h;
                __hip_atomic_store(&hdst[(size_t)(bbase + s * 16 + quad * 4 + i) * 512 + colbase + col_l],
                                   f2bf(h), __ATOMIC_RELAXED, __HIP_MEMORY_SCOPE_AGENT);
            }
        }
        group_bar(ctr, 32u * (t + 2));
    }
    // final hidden state -> d_out hn region (fp32)
    #pragma unroll
    for (int s = 0; s < 2; ++s)
        #pragma unroll
        for (int i = 0; i < 4; ++i)
            hn_out[(size_t)(bbase + s * 16 + quad * 4 + i) * 512 + colbase + col_l] = hs[s][i];
}

// ---------------- epilogue: out2 = relu(relu(h)@W3.T + b3); params = out2.Wh[cult] + bh
// hfin = bf16 final h (hbuf0: step 127 wrote buffer (127+1)&1 = 0)
__launch_bounds__(256)
__global__ void k_head(const u16* __restrict__ hfin, const float* __restrict__ W3,
                       const float* __restrict__ b3, const int* __restrict__ cult,
                       const float* __restrict__ Wh, const float* __restrict__ bh,
                       float* __restrict__ params) {
    __shared__ float out2[16][264];
    const int tid = threadIdx.x, wave = tid >> 6, lane = tid & 63;
    const int col_l = lane & 15, quad = lane >> 4;
    const int bbase = blockIdx.x * 16;            // 64 blocks x 16 batches

    f32x4 z4 = { 0.f, 0.f, 0.f, 0.f };
    f32x4 acc[4];
    #pragma unroll
    for (int nt = 0; nt < 4; ++nt) acc[nt] = z4;

    #pragma unroll
    for (int kc = 0; kc < 16; ++kc) {
        short8 a = *(const short8*)(hfin + (size_t)(bbase + col_l) * 512 + kc * 32 + quad * 8);
        #pragma unroll
        for (int e = 0; e < 8; ++e) {             // relu on packed bf16 (sign test)
            u16 v = (u16)a[e];
            a[e] = (short)((v & 0x8000u) ? 0 : v);
        }
        #pragma unroll
        for (int nt = 0; nt < 4; ++nt) {
            int nrow = wave * 64 + nt * 16 + col_l;
            const float* wr = W3 + (size_t)nrow * 512 + kc * 32 + quad * 8;
            short8 b;
            #pragma unroll
            for (int e = 0; e < 8; ++e) b[e] = (short)f2bf(wr[e]);
            acc[nt] = mfma16(a, b, acc[nt]);
        }
    }
    #pragma unroll
    for (int nt = 0; nt < 4; ++nt) {
        int ncol = wave * 64 + nt * 16 + col_l;
        float bias = b3[ncol];
        #pragma unroll
        for (int i = 0; i < 4; ++i) {
            float v = acc[nt][i] + bias;
            out2[quad * 4 + i][ncol] = v > 0.f ? v : 0.f;
        }
    }
    __syncthreads();
    // per-cultivar head: 16 batches x 16 outputs = 256 threads, 256-MAC dot each
    int b_local = tid >> 4, o2 = tid & 15;
    int batch = bbase + b_local;
    int c = cult[batch];
    float acc2 = bh[c * 16 + o2];
    const float* wrow = Wh + (size_t)(c * 16 + o2) * 256;
    for (int d = 0; d < 256; ++d) acc2 += out2[b_local][d] * wrow[d];
    params[(size_t)batch * 16 + o2] = acc2;
}

// ---------------- launcher ----------------
extern "C" void kernel_launch(void* const* d_in, const int* in_sizes, int n_in,
                              void* d_out, int out_size, void* d_ws, size_t ws_size,
                              hipStream_t stream) {
    (void)in_sizes; (void)n_in; (void)out_size; (void)ws_size;
    const float* input = (const float*)d_in[0];
    const float* hn    = (const float*)d_in[1];
    const int*   cult  = (const int*)d_in[2];
    const float* W1    = (const float*)d_in[3];
    const float* b1    = (const float*)d_in[4];
    const float* W2    = (const float*)d_in[5];
    const float* b2    = (const float*)d_in[6];
    const float* W_ih  = (const float*)d_in[7];
    const float* W_hh  = (const float*)d_in[8];
    const float* b_ih  = (const float*)d_in[9];
    const float* b_hh  = (const float*)d_in[10];
    const float* W3    = (const float*)d_in[11];
    const float* b3    = (const float*)d_in[12];
    const float* Wh    = (const float*)d_in[13];
    const float* bh    = (const float*)d_in[14];

    char* ws = (char*)d_ws;
    u16*      hbuf0 = (u16*)(ws + WS_HBUF0);
    u16*      hbuf1 = (u16*)(ws + WS_HBUF1);
    float*    W21   = (float*)(ws + WS_W21);
    float*    b21   = (float*)(ws + WS_B21);
    u16*      Weff  = (u16*)(ws + WS_WEFF);
    float*    beff  = (float*)(ws + WS_BEFF);
    unsigned* ctrs  = (unsigned*)(ws + WS_CTRS);

    float* out    = (float*)d_out;
    float* params = out;            // 1024*16 fp32
    float* hnout  = out + 16384;    // 1024*512 fp32

    k_prep0<<<64, 256, 0, stream>>>(W1, b1, W2, b2, W21, b21, ctrs);
    k_prep1<<<192, 256, 0, stream>>>(W_ih, b_ih, W21, b21, Weff, beff);
    k_gru<<<256, 256, 0, stream>>>(input, hn, W_hh, b_hh, Weff, beff,
                                   hbuf0, hbuf1, ctrs, hnout);
    k_head<<<64, 256, 0, stream>>>(hbuf0, W3, b3, cult, Wh, bh, params);
}

// Round 4
// 1517.947 us; speedup vs baseline: 3.9216x; 1.0088x over previous
//
#include <hip/hip_runtime.h>

// ---------------------------------------------------------------------------
// FCGRU (fp32 globals; bf16 in MFMA frags):
//   input(1024,128,32) -> FC(32->256) -> FC(256->512) -> GRU(512) over T=128
//   -> relu -> FC(512->256)+relu -> per-cultivar head (256->16)
// Input-side linears collapse: gx = input @ (W_ih@W2@W1).T + b_eff  (K=32 MFMA).
// Persistent GRU: 8 groups x 32 blocks; cross-block h via RELAXED AGENT (sc1)
// loads/stores (coherent at MALL, no cache maintenance). Barrier = per-block
// FLAG STORES (no atomic RMW) + one lane-parallel poll of the 128-B flag line.
// gx MFMAs overlap the barrier-wait window; x-frags preloaded a step ahead.
// ---------------------------------------------------------------------------

#define T_STEPS 128

typedef __attribute__((ext_vector_type(8))) short short8;
typedef __attribute__((ext_vector_type(4))) float f32x4;
typedef unsigned short u16;
typedef unsigned long long u64;

static __device__ __forceinline__ u16 f2bf(float f) {
    unsigned int u = __builtin_bit_cast(unsigned int, f);
    u += 0x7FFFu + ((u >> 16) & 1u);          // round-to-nearest-even
    return (u16)(u >> 16);
}
static __device__ __forceinline__ f32x4 mfma16(short8 a, short8 b, f32x4 c) {
    return __builtin_amdgcn_mfma_f32_16x16x32_bf16(a, b, c, 0, 0, 0);
}
// 16B device-coherent load/store of h (2x u64 relaxed agent atomics -> sc1)
static __device__ __forceinline__ short8 ld_h16(const u16* p) {
    const u64* q = (const u64*)p;
    u64 lo = __hip_atomic_load(q + 0, __ATOMIC_RELAXED, __HIP_MEMORY_SCOPE_AGENT);
    u64 hi = __hip_atomic_load(q + 1, __ATOMIC_RELAXED, __HIP_MEMORY_SCOPE_AGENT);
    struct { u64 a, b; } w{lo, hi};
    return __builtin_bit_cast(short8, w);
}
static __device__ __forceinline__ void st_h16(u16* p, short8 v) {
    struct W { u64 a, b; } w = __builtin_bit_cast(W, v);
    u64* q = (u64*)p;
    __hip_atomic_store(q + 0, w.a, __ATOMIC_RELAXED, __HIP_MEMORY_SCOPE_AGENT);
    __hip_atomic_store(q + 1, w.b, __ATOMIC_RELAXED, __HIP_MEMORY_SCOPE_AGENT);
}

// ---------------- workspace layout (bytes) ----------------
#define WS_HBUF0 0           // 1024*512*2 bf16 h buffer 0
#define WS_HBUF1 1048576     // 1024*512*2 bf16 h buffer 1
#define WS_W21   2097152     // 512*32*4 fp32 W2@W1
#define WS_B21   2162688     // 512*4
#define WS_WEFF  2164736     // 1536*32*2 bf16 W_ih@W2@W1
#define WS_BEFF  2263040     // 1536*4
#define WS_FLAGS 2269184     // 8 groups x 32 blocks x 4B = 1024 (128B/group)

// ---------------- prologue 0: W21 = W2@W1 (fp32); b21 = W2@b1 + b2; zero flags
__global__ void k_prep0(const float* __restrict__ W1, const float* __restrict__ b1,
                        const float* __restrict__ W2, const float* __restrict__ b2,
                        float* __restrict__ W21, float* __restrict__ b21,
                        unsigned* __restrict__ flags) {
    if (blockIdx.x == 0)
        __hip_atomic_store(&flags[threadIdx.x], 0u, __ATOMIC_RELAXED, __HIP_MEMORY_SCOPE_AGENT);
    int gid = blockIdx.x * 256 + threadIdx.x;   // 64 blocks: 512*32 outputs
    int k = gid >> 5, d = gid & 31;
    float acc = 0.f;
    for (int j = 0; j < 256; ++j)
        acc += W2[k * 256 + j] * W1[j * 32 + d];
    W21[k * 32 + d] = acc;
    if (d == 0) {
        float bb = b2[k];
        for (int j = 0; j < 256; ++j) bb += W2[k * 256 + j] * b1[j];
        b21[k] = bb;
    }
}

// ---------------- prologue 1: Weff = bf16(W_ih@W21); beff = W_ih@b21 + b_ih
__global__ void k_prep1(const float* __restrict__ W_ih, const float* __restrict__ b_ih,
                        const float* __restrict__ W21, const float* __restrict__ b21,
                        u16* __restrict__ Weff, float* __restrict__ beff) {
    int gid = blockIdx.x * 256 + threadIdx.x;   // 192 blocks: 1536*32 outputs
    int g = gid >> 5, d = gid & 31;
    float acc = 0.f;
    for (int k = 0; k < 512; ++k)
        acc += W_ih[g * 512 + k] * W21[k * 32 + d];
    Weff[g * 32 + d] = f2bf(acc);
    if (d == 0) {
        float bb = b_ih[g];
        for (int k = 0; k < 512; ++k) bb += W_ih[g * 512 + k] * b21[k];
        beff[g] = bb;
    }
}

// ---------------- flag barrier (no RMW) ----------------
// Arrival: AFTER __syncthreads() (compiler drains vmcnt(0) -> all waves' sc1
// h-stores are at the MALL), thread 0 stores epoch v to its own 4B slot.
// Wait: wave 0 polls the group's 128-B flag line with one 32-lane sc1 load +
// ballot; everyone else parks at the trailing __syncthreads.
static __device__ __forceinline__ void bar_arrive(unsigned* gflags, int slot, unsigned v) {
    __syncthreads();
    if (threadIdx.x == 0)
        __hip_atomic_store(&gflags[slot], v, __ATOMIC_RELAXED, __HIP_MEMORY_SCOPE_AGENT);
}
static __device__ __forceinline__ void bar_wait(const unsigned* gflags, unsigned v) {
    if (threadIdx.x < 64) {
        int idx = threadIdx.x & 31;
        for (;;) {
            unsigned f = __hip_atomic_load(&gflags[idx], __ATOMIC_RELAXED, __HIP_MEMORY_SCOPE_AGENT);
            if (__ballot(f >= v) == ~0ull) break;
            __builtin_amdgcn_s_sleep(1);
        }
    }
    __syncthreads();
}

// ---------------- GRU persistent kernel ----------------
// grid 256 x 256. group = blk&7 (128 batches), colgroup = blk>>3 (16 h-cols).
__launch_bounds__(256, 1)
__global__ void k_gru(const float* __restrict__ input, const float* __restrict__ hn,
                      const float* __restrict__ W_hh, const float* __restrict__ b_hh,
                      const u16* __restrict__ Weff, const float* __restrict__ beff,
                      u16* __restrict__ hbuf0, u16* __restrict__ hbuf1,
                      unsigned* __restrict__ flags, float* __restrict__ hn_out) {
    __shared__ __align__(16) u16 whh[48][520];   // 48 rows x 512 bf16, +8 pad

    const int tid  = threadIdx.x;
    const int wave = tid >> 6, lane = tid & 63;
    const int col_l = lane & 15, quad = lane >> 4;
    const int blk = blockIdx.x;
    const int grp = blk & 7, colg = blk >> 3;
    const int colbase = colg * 16;
    const int bbase = grp * 128 + wave * 32;
    unsigned* gflags = flags + grp * 32;

    // stage this block's 48 W_hh rows (r,z,n x 16 cols), fp32 -> bf16 LDS
    for (int idx = tid; idx < 48 * 64; idx += 256) {
        int r = idx >> 6, ch = idx & 63;
        int g3 = r >> 4, c = r & 15;
        const float* src = W_hh + (size_t)(g3 * 512 + colbase + c) * 512 + ch * 8;
        short8 v;
        #pragma unroll
        for (int e = 0; e < 8; ++e) v[e] = (short)f2bf(src[e]);
        *(short8*)(&whh[r][ch * 8]) = v;
    }
    // copy this block's 4 batches of hn -> hbuf0 (bf16, sc1 stores)
    {
        int b = grp * 128 + colg * 4 + wave;     // 1 row per wave
        const float* src = hn + (size_t)b * 512 + lane * 8;
        short8 v;
        #pragma unroll
        for (int e = 0; e < 8; ++e) v[e] = (short)f2bf(src[e]);
        st_h16(hbuf0 + (size_t)b * 512 + lane * 8, v);
    }
    // register-resident W_eff B-frags (bf16) + per-column biases (fp32)
    short8 bwx[3];
    float bx[3], bhh[3];
    #pragma unroll
    for (int g3 = 0; g3 < 3; ++g3) {
        int nrow = g3 * 512 + colbase + col_l;
        bwx[g3] = *(const short8*)(Weff + nrow * 32 + quad * 8);
        bx[g3]  = beff[nrow];
        bhh[g3] = b_hh[nrow];
    }
    // fp32 carried h-state, C-tile layout: batch = bbase + s*16 + quad*4 + i
    float hs[2][4];
    #pragma unroll
    for (int s = 0; s < 2; ++s)
        #pragma unroll
        for (int i = 0; i < 4; ++i)
            hs[s][i] = hn[(size_t)(bbase + s * 16 + quad * 4 + i) * 512 + colbase + col_l];

    // preload x-frags for t=0 (fp32 -> bf16 in regs)
    short8 xa[2];
    #pragma unroll
    for (int s = 0; s < 2; ++s) {
        const float* xp = input + (size_t)(bbase + s * 16 + col_l) * 4096 + quad * 8;
        #pragma unroll
        for (int e = 0; e < 8; ++e) xa[s][e] = (short)f2bf(xp[e]);
    }

    bar_arrive(gflags, colg, 1u);                 // hn staging published

    u16* bufs[2] = { hbuf0, hbuf1 };
    #pragma unroll 1
    for (int t = 0; t < T_STEPS; ++t) {
        const u16* hsrc = bufs[t & 1];
        u16* hdst = bufs[(t + 1) & 1];

        // gx seed in the barrier-wait window (h-independent, frags in regs)
        f32x4 ar[2], az[2], anx[2], anh[2];
        #pragma unroll
        for (int s = 0; s < 2; ++s) {
            f32x4 z4 = { 0.f, 0.f, 0.f, 0.f };
            ar[s]  = mfma16(xa[s], bwx[0], z4);
            az[s]  = mfma16(xa[s], bwx[1], z4);
            anx[s] = mfma16(xa[s], bwx[2], z4);
            anh[s] = z4;
        }

        bar_wait(gflags, (unsigned)(t + 1));      // h(t) visible group-wide

        // prefetch the whole step's A-frags (sc1, pipelined)
        short8 a0f[16], a1f[16];
        #pragma unroll
        for (int kc = 0; kc < 16; ++kc) {
            a0f[kc] = ld_h16(hsrc + (size_t)(bbase + col_l) * 512 + kc * 32 + quad * 8);
            a1f[kc] = ld_h16(hsrc + (size_t)(bbase + 16 + col_l) * 512 + kc * 32 + quad * 8);
        }
        // preload x-frags for t+1 (cached loads; latency hidden behind gh)
        {
            int tn = (t + 1) & (T_STEPS - 1);     // last iter reloads t=0, unused
            #pragma unroll
            for (int s = 0; s < 2; ++s) {
                const float* xp = input + (size_t)(bbase + s * 16 + col_l) * 4096 + tn * 32 + quad * 8;
                #pragma unroll
                for (int e = 0; e < 8; ++e) xa[s][e] = (short)f2bf(xp[e]);
            }
        }
        // gh: K=512 over bf16 h (A from registers, B from LDS)
        #pragma unroll
        for (int kc = 0; kc < 16; ++kc) {
            short8 br = *(const short8*)(&whh[ 0 + col_l][kc * 32 + quad * 8]);
            short8 bz = *(const short8*)(&whh[16 + col_l][kc * 32 + quad * 8]);
            short8 bn = *(const short8*)(&whh[32 + col_l][kc * 32 + quad * 8]);
            ar[0]  = mfma16(a0f[kc], br, ar[0]);   ar[1]  = mfma16(a1f[kc], br, ar[1]);
            az[0]  = mfma16(a0f[kc], bz, az[0]);   az[1]  = mfma16(a1f[kc], bz, az[1]);
            anh[0] = mfma16(a0f[kc], bn, anh[0]);  anh[1] = mfma16(a1f[kc], bn, anh[1]);
        }
        // gates + state update (fp32), store bf16 h_new (sc1 stores)
        #pragma unroll
        for (int s = 0; s < 2; ++s) {
            #pragma unroll
            for (int i = 0; i < 4; ++i) {
                float r = 1.f / (1.f + __expf(-(ar[s][i] + bx[0] + bhh[0])));
                float z = 1.f / (1.f + __expf(-(az[s][i] + bx[1] + bhh[1])));
                float np = anx[s][i] + bx[2] + r * (anh[s][i] + bhh[2]);
                float e  = __expf(-2.f * fabsf(np));
                float nn = __builtin_copysignf((1.f - e) / (1.f + e), np);
                float h  = (1.f - z) * nn + z * hs[s][i];
                hs[s][i] = h;
                __hip_atomic_store(&hdst[(size_t)(bbase + s * 16 + quad * 4 + i) * 512 + colbase + col_l],
                                   f2bf(h), __ATOMIC_RELAXED, __HIP_MEMORY_SCOPE_AGENT);
            }
        }
        bar_arrive(gflags, colg, (unsigned)(t + 2));   // publish h(t+1)
    }
    // final hidden state -> d_out hn region (fp32)
    #pragma unroll
    for (int s = 0; s < 2; ++s)
        #pragma unroll
        for (int i = 0; i < 4; ++i)
            hn_out[(size_t)(bbase + s * 16 + quad * 4 + i) * 512 + colbase + col_l] = hs[s][i];
}

// ---------------- epilogue: out2 = relu(relu(h)@W3.T + b3); params = out2.Wh[cult] + bh
// hfin = bf16 final h (hbuf0: step 127 wrote buffer (127+1)&1 = 0)
__launch_bounds__(256)
__global__ void k_head(const u16* __restrict__ hfin, const float* __restrict__ W3,
                       const float* __restrict__ b3, const int* __restrict__ cult,
                       const float* __restrict__ Wh, const float* __restrict__ bh,
                       float* __restrict__ params) {
    __shared__ float out2[16][264];
    const int tid = threadIdx.x, wave = tid >> 6, lane = tid & 63;
    const int col_l = lane & 15, quad = lane >> 4;
    const int bbase = blockIdx.x * 16;            // 64 blocks x 16 batches

    f32x4 z4 = { 0.f, 0.f, 0.f, 0.f };
    f32x4 acc[4];
    #pragma unroll
    for (int nt = 0; nt < 4; ++nt) acc[nt] = z4;

    #pragma unroll
    for (int kc = 0; kc < 16; ++kc) {
        short8 a = *(const short8*)(hfin + (size_t)(bbase + col_l) * 512 + kc * 32 + quad * 8);
        #pragma unroll
        for (int e = 0; e < 8; ++e) {             // relu on packed bf16 (sign test)
            u16 v = (u16)a[e];
            a[e] = (short)((v & 0x8000u) ? 0 : v);
        }
        #pragma unroll
        for (int nt = 0; nt < 4; ++nt) {
            int nrow = wave * 64 + nt * 16 + col_l;
            const float* wr = W3 + (size_t)nrow * 512 + kc * 32 + quad * 8;
            short8 b;
            #pragma unroll
            for (int e = 0; e < 8; ++e) b[e] = (short)f2bf(wr[e]);
            acc[nt] = mfma16(a, b, acc[nt]);
        }
    }
    #pragma unroll
    for (int nt = 0; nt < 4; ++nt) {
        int ncol = wave * 64 + nt * 16 + col_l;
        float bias = b3[ncol];
        #pragma unroll
        for (int i = 0; i < 4; ++i) {
            float v = acc[nt][i] + bias;
            out2[quad * 4 + i][ncol] = v > 0.f ? v : 0.f;
        }
    }
    __syncthreads();
    // per-cultivar head: 16 batches x 16 outputs = 256 threads, 256-MAC dot each
    int b_local = tid >> 4, o2 = tid & 15;
    int batch = bbase + b_local;
    int c = cult[batch];
    float acc2 = bh[c * 16 + o2];
    const float* wrow = Wh + (size_t)(c * 16 + o2) * 256;
    for (int d = 0; d < 256; ++d) acc2 += out2[b_local][d] * wrow[d];
    params[(size_t)batch * 16 + o2] = acc2;
}

// ---------------- launcher ----------------
extern "C" void kernel_launch(void* const* d_in, const int* in_sizes, int n_in,
                              void* d_out, int out_size, void* d_ws, size_t ws_size,
                              hipStream_t stream) {
    (void)in_sizes; (void)n_in; (void)out_size; (void)ws_size;
    const float* input = (const float*)d_in[0];
    const float* hn    = (const float*)d_in[1];
    const int*   cult  = (const int*)d_in[2];
    const float* W1    = (const float*)d_in[3];
    const float* b1    = (const float*)d_in[4];
    const float* W2    = (const float*)d_in[5];
    const float* b2    = (const float*)d_in[6];
    const float* W_ih  = (const float*)d_in[7];
    const float* W_hh  = (const float*)d_in[8];
    const float* b_ih  = (const float*)d_in[9];
    const float* b_hh  = (const float*)d_in[10];
    const float* W3    = (const float*)d_in[11];
    const float* b3    = (const float*)d_in[12];
    const float* Wh    = (const float*)d_in[13];
    const float* bh    = (const float*)d_in[14];

    char* ws = (char*)d_ws;
    u16*      hbuf0 = (u16*)(ws + WS_HBUF0);
    u16*      hbuf1 = (u16*)(ws + WS_HBUF1);
    float*    W21   = (float*)(ws + WS_W21);
    float*    b21   = (float*)(ws + WS_B21);
    u16*      Weff  = (u16*)(ws + WS_WEFF);
    float*    beff  = (float*)(ws + WS_BEFF);
    unsigned* flags = (unsigned*)(ws + WS_FLAGS);

    float* out    = (float*)d_out;
    float* params = out;            // 1024*16 fp32
    float* hnout  = out + 16384;    // 1024*512 fp32

    k_prep0<<<64, 256, 0, stream>>>(W1, b1, W2, b2, W21, b21, flags);
    k_prep1<<<192, 256, 0, stream>>>(W_ih, b_ih, W21, b21, Weff, beff);
    k_gru<<<256, 256, 0, stream>>>(input, hn, W_hh, b_hh, Weff, beff,
                                   hbuf0, hbuf1, flags, hnout);
    k_head<<<64, 256, 0, stream>>>(hbuf0, W3, b3, cult, Wh, bh, params);
}

// Round 5
// 938.387 us; speedup vs baseline: 6.3437x; 1.6176x over previous
//
#include <hip/hip_runtime.h>

// ---------------------------------------------------------------------------
// FCGRU (fp32 globals; bf16 in MFMA frags):
//   input(1024,128,32) -> FC(32->256) -> FC(256->512) -> GRU(512) over T=128
//   -> relu -> FC(512->256)+relu -> per-cultivar head (256->16)
// Input-side linears collapse: gx = input @ (W_ih@W2@W1).T + b_eff  (K=32 MFMA).
// Persistent GRU: 16 groups x 16 col-blocks. Cross-block h via sc1 (relaxed
// agent atomics, MALL-coherent). Per step, each block COOPERATIVELY stages its
// group's h slab (64 rows x 1KB) into LDS with lane-contiguous coalesced sc1
// loads (2 phases of 32 rows), then MFMAs read frags from LDS via ds_read_b64
// (pitch 516 u16 -> ~conflict-free). W_hh 32-col slice resident in LDS (97KB).
// Flag-array barrier (no RMW). Dynamic LDS 132KB.
// ---------------------------------------------------------------------------

#define T_STEPS 128
#define PITCH   516             // u16 row pitch in LDS (512 + 4): 258 dw = 2 mod 32
#define WHH_ROWS 96
#define SLAB_ROWS 32
#define LDS_BYTES ((WHH_ROWS + SLAB_ROWS) * PITCH * 2)   // 132,096 B

typedef __attribute__((ext_vector_type(8))) short short8;
typedef __attribute__((ext_vector_type(4))) short short4v;
typedef __attribute__((ext_vector_type(4))) float f32x4;
typedef __attribute__((ext_vector_type(4))) float float4v;
typedef unsigned short u16;
typedef unsigned long long u64;

static __device__ __forceinline__ u16 f2bf(float f) {
    unsigned int u = __builtin_bit_cast(unsigned int, f);
    u += 0x7FFFu + ((u >> 16) & 1u);          // round-to-nearest-even
    return (u16)(u >> 16);
}
static __device__ __forceinline__ f32x4 mfma16(short8 a, short8 b, f32x4 c) {
    return __builtin_amdgcn_mfma_f32_16x16x32_bf16(a, b, c, 0, 0, 0);
}
// 16B device-coherent store of h (2x u64 relaxed agent atomics -> sc1)
static __device__ __forceinline__ void st_h16(u16* p, short8 v) {
    struct W { u64 a, b; } w = __builtin_bit_cast(W, v);
    u64* q = (u64*)p;
    __hip_atomic_store(q + 0, w.a, __ATOMIC_RELAXED, __HIP_MEMORY_SCOPE_AGENT);
    __hip_atomic_store(q + 1, w.b, __ATOMIC_RELAXED, __HIP_MEMORY_SCOPE_AGENT);
}
static __device__ __forceinline__ u64 ld_sc1_u64(const u16* p) {
    return __hip_atomic_load((const u64*)p, __ATOMIC_RELAXED, __HIP_MEMORY_SCOPE_AGENT);
}
// 16B LDS fragment read as two b64 (8B-aligned; pitch makes this ~2-way = free)
static __device__ __forceinline__ short8 lds8(const u16* p) {
    u64 lo = *(const u64*)p;
    u64 hi = *(const u64*)(p + 4);
    struct W { u64 a, b; } w{lo, hi};
    return __builtin_bit_cast(short8, w);
}

// ---------------- workspace layout (bytes) ----------------
#define WS_HBUF0 0           // 1024*512*2 bf16 h buffer 0
#define WS_HBUF1 1048576     // 1024*512*2 bf16 h buffer 1
#define WS_W21   2097152     // 512*32*4 fp32 W2@W1
#define WS_B21   2162688     // 512*4
#define WS_WEFF  2164736     // 1536*32*2 bf16 W_ih@W2@W1
#define WS_BEFF  2263040     // 1536*4
#define WS_FLAGS 2269184     // 16 groups x 32 slots x 4B = 2048

// ---------------- prologue 0: W21 = W2@W1 (fp32); b21 = W2@b1 + b2; zero flags
__global__ void k_prep0(const float* __restrict__ W1, const float* __restrict__ b1,
                        const float* __restrict__ W2, const float* __restrict__ b2,
                        float* __restrict__ W21, float* __restrict__ b21,
                        unsigned* __restrict__ flags) {
    if (blockIdx.x == 0) {
        __hip_atomic_store(&flags[threadIdx.x], 0u, __ATOMIC_RELAXED, __HIP_MEMORY_SCOPE_AGENT);
        __hip_atomic_store(&flags[256 + threadIdx.x], 0u, __ATOMIC_RELAXED, __HIP_MEMORY_SCOPE_AGENT);
    }
    int gid = blockIdx.x * 256 + threadIdx.x;   // 64 blocks: 512*32 outputs
    int k = gid >> 5, d = gid & 31;
    float acc = 0.f;
    for (int j = 0; j < 256; ++j)
        acc += W2[k * 256 + j] * W1[j * 32 + d];
    W21[k * 32 + d] = acc;
    if (d == 0) {
        float bb = b2[k];
        for (int j = 0; j < 256; ++j) bb += W2[k * 256 + j] * b1[j];
        b21[k] = bb;
    }
}

// ---------------- prologue 1: Weff = bf16(W_ih@W21); beff = W_ih@b21 + b_ih
__global__ void k_prep1(const float* __restrict__ W_ih, const float* __restrict__ b_ih,
                        const float* __restrict__ W21, const float* __restrict__ b21,
                        u16* __restrict__ Weff, float* __restrict__ beff) {
    int gid = blockIdx.x * 256 + threadIdx.x;   // 192 blocks: 1536*32 outputs
    int g = gid >> 5, d = gid & 31;
    float acc = 0.f;
    for (int k = 0; k < 512; ++k)
        acc += W_ih[g * 512 + k] * W21[k * 32 + d];
    Weff[g * 32 + d] = f2bf(acc);
    if (d == 0) {
        float bb = b_ih[g];
        for (int k = 0; k < 512; ++k) bb += W_ih[g * 512 + k] * b21[k];
        beff[g] = bb;
    }
}

// ---------------- flag barrier (no RMW) ----------------
static __device__ __forceinline__ void bar_arrive(unsigned* gflags, int slot, unsigned v) {
    __syncthreads();      // drains vmcnt(0): all waves' sc1 h-stores at MALL
    if (threadIdx.x == 0)
        __hip_atomic_store(&gflags[slot], v, __ATOMIC_RELAXED, __HIP_MEMORY_SCOPE_AGENT);
}
static __device__ __forceinline__ void bar_wait(const unsigned* gflags, unsigned v) {
    if (threadIdx.x < 64) {
        int idx = threadIdx.x & 15;
        for (;;) {
            unsigned f = __hip_atomic_load(&gflags[idx], __ATOMIC_RELAXED, __HIP_MEMORY_SCOPE_AGENT);
            if (__ballot(f >= v) == ~0ull) break;
            __builtin_amdgcn_s_sleep(1);
        }
    }
    __syncthreads();
}

// ---------------- GRU persistent kernel ----------------
// grid 256 x 256. grp = blk&15 (owns 64 batches), colg = blk>>4 (32 h-cols).
// wave: wcol = wave&1 (16-col tile), wm = wave>>1 (m-tile within phase).
// phase p covers group-batch rows [p*32, p*32+32).
__launch_bounds__(256, 1)
__global__ void k_gru(const float* __restrict__ input, const float* __restrict__ hn,
                      const float* __restrict__ W_hh, const float* __restrict__ b_hh,
                      const u16* __restrict__ Weff, const float* __restrict__ beff,
                      u16* __restrict__ hbuf0, u16* __restrict__ hbuf1,
                      unsigned* __restrict__ flags, float* __restrict__ hn_out) {
    extern __shared__ __align__(16) u16 lds[];
    u16* whh  = lds;                       // [96][PITCH]  bf16 W_hh slice
    u16* slab = lds + WHH_ROWS * PITCH;    // [32][PITCH]  bf16 h phase-slab

    const int tid  = threadIdx.x;
    const int wave = tid >> 6, lane = tid & 63;
    const int col_l = lane & 15, quad = lane >> 4;
    const int blk = blockIdx.x;
    const int grp = blk & 15, colg = blk >> 4;
    const int colbase = colg * 32;
    const int grpbase = grp * 64;
    const int wcol = wave & 1, wm = wave >> 1;
    const int cb = colbase + wcol * 16;         // wave's 16-col tile base
    unsigned* gflags = flags + grp * 32;

    // stage W_hh slice (3 gates x 32 cols = 96 rows), fp32 -> bf16 LDS
    for (int idx = tid; idx < WHH_ROWS * 64; idx += 256) {
        int rr = idx >> 6, ch = idx & 63;
        int g3 = rr >> 5, c = rr & 31;
        const float* src = W_hh + (size_t)(g3 * 512 + colbase + c) * 512 + ch * 8;
        short4v lo, hi;
        #pragma unroll
        for (int e = 0; e < 4; ++e) { lo[e] = (short)f2bf(src[e]); hi[e] = (short)f2bf(src[4 + e]); }
        *(u64*)&whh[rr * PITCH + ch * 8]     = __builtin_bit_cast(u64, lo);
        *(u64*)&whh[rr * PITCH + ch * 8 + 4] = __builtin_bit_cast(u64, hi);
    }
    // copy this block's 4 rows of hn -> hbuf0 (bf16, sc1, own group's rows)
    {
        int b = grpbase + colg * 4 + wave;       // 1 row per wave
        const float* src = hn + (size_t)b * 512 + lane * 8;
        short8 v;
        #pragma unroll
        for (int e = 0; e < 8; ++e) v[e] = (short)f2bf(src[e]);
        st_h16(hbuf0 + (size_t)b * 512 + lane * 8, v);
    }
    // register-resident W_eff B-frags (bf16) + per-column biases (fp32)
    short8 bwx[3];
    float bx[3], bhh[3];
    #pragma unroll
    for (int g3 = 0; g3 < 3; ++g3) {
        int nr = g3 * 512 + cb + col_l;
        bwx[g3] = *(const short8*)(Weff + nr * 32 + quad * 8);
        bx[g3]  = beff[nr];
        bhh[g3] = b_hh[nr];
    }
    // fp32 carried h-state: batch = grpbase + p*32 + wm*16 + quad*4 + i, col = cb+col_l
    float hs[2][4];
    #pragma unroll
    for (int p = 0; p < 2; ++p)
        #pragma unroll
        for (int i = 0; i < 4; ++i)
            hs[p][i] = hn[(size_t)(grpbase + p * 32 + wm * 16 + quad * 4 + i) * 512 + cb + col_l];

    bar_arrive(gflags, colg, 1u);                 // hn staging published

    u16* bufs[2] = { hbuf0, hbuf1 };
    #pragma unroll 1
    for (int t = 0; t < T_STEPS; ++t) {
        const u16* hsrc = bufs[t & 1];
        u16* hdst = bufs[(t + 1) & 1];

        // x loads for both phases (normal cached loads; h-independent)
        float xf[2][8];
        #pragma unroll
        for (int p = 0; p < 2; ++p) {
            const float* xp = input + (size_t)(grpbase + p * 32 + wm * 16 + col_l) * 4096 + t * 32 + quad * 8;
            float4v a = *(const float4v*)xp;
            float4v b = *(const float4v*)(xp + 4);
            #pragma unroll
            for (int e = 0; e < 4; ++e) { xf[p][e] = a[e]; xf[p][4 + e] = b[e]; }
        }

        bar_wait(gflags, (unsigned)(t + 1));      // h(t) visible group-wide

        // ---- phase 0: stage rows [0,32) coalesced (lane-contiguous sc1) ----
        u64 stg0[16];
        #pragma unroll
        for (int r8 = 0; r8 < 8; ++r8)
            #pragma unroll
            for (int j = 0; j < 2; ++j)
                stg0[r8 * 2 + j] = ld_sc1_u64(hsrc + (size_t)(grpbase + wave * 8 + r8) * 512 + j * 256 + lane * 4);
        #pragma unroll
        for (int r8 = 0; r8 < 8; ++r8)
            #pragma unroll
            for (int j = 0; j < 2; ++j)
                *(u64*)&slab[(wave * 8 + r8) * PITCH + j * 256 + lane * 4] = stg0[r8 * 2 + j];
        __syncthreads();                          // slab P0 ready

        // issue phase-1 staging loads now (latency hidden behind P0 compute)
        u64 stg1[16];
        #pragma unroll
        for (int r8 = 0; r8 < 8; ++r8)
            #pragma unroll
            for (int j = 0; j < 2; ++j)
                stg1[r8 * 2 + j] = ld_sc1_u64(hsrc + (size_t)(grpbase + 32 + wave * 8 + r8) * 512 + j * 256 + lane * 4);

        // ---- compute phases ----
        #pragma unroll
        for (int p = 0; p < 2; ++p) {
            if (p == 1) {
                __syncthreads();                  // all waves done reading P0 slab
                #pragma unroll
                for (int r8 = 0; r8 < 8; ++r8)
                    #pragma unroll
                    for (int j = 0; j < 2; ++j)
                        *(u64*)&slab[(wave * 8 + r8) * PITCH + j * 256 + lane * 4] = stg1[r8 * 2 + j];
                __syncthreads();                  // slab P1 ready
            }
            // gx seed (K=32 MFMA; x fp32 -> bf16)
            short8 ax;
            #pragma unroll
            for (int e = 0; e < 8; ++e) ax[e] = (short)f2bf(xf[p][e]);
            f32x4 z4 = { 0.f, 0.f, 0.f, 0.f };
            f32x4 ar  = mfma16(ax, bwx[0], z4);
            f32x4 az  = mfma16(ax, bwx[1], z4);
            f32x4 anx = mfma16(ax, bwx[2], z4);
            f32x4 anh = z4;
            // gh: K=512, A from slab, B from whh (paired ds_read_b64)
            const int arow = (wm * 16 + col_l) * PITCH;
            const int brr  = (wcol * 16 + col_l) * PITCH;
            #pragma unroll
            for (int kc = 0; kc < 16; ++kc) {
                const int ko = kc * 32 + quad * 8;
                short8 a  = lds8(slab + arow + ko);
                short8 br = lds8(whh + brr + ko);
                short8 bz = lds8(whh + 32 * PITCH + brr + ko);
                short8 bn = lds8(whh + 64 * PITCH + brr + ko);
                ar  = mfma16(a, br, ar);
                az  = mfma16(a, bz, az);
                anh = mfma16(a, bn, anh);
            }
            // gates + state update (fp32), sc1 bf16 h_new stores
            #pragma unroll
            for (int i = 0; i < 4; ++i) {
                float r = 1.f / (1.f + __expf(-(ar[i] + bx[0] + bhh[0])));
                float z = 1.f / (1.f + __expf(-(az[i] + bx[1] + bhh[1])));
                float np = anx[i] + bx[2] + r * (anh[i] + bhh[2]);
                float e  = __expf(-2.f * fabsf(np));
                float nn = __builtin_copysignf((1.f - e) / (1.f + e), np);
                float h  = (1.f - z) * nn + z * hs[p][i];
                hs[p][i] = h;
                int b = grpbase + p * 32 + wm * 16 + quad * 4 + i;
                __hip_atomic_store(&hdst[(size_t)b * 512 + cb + col_l], f2bf(h),
                                   __ATOMIC_RELAXED, __HIP_MEMORY_SCOPE_AGENT);
            }
        }
        bar_arrive(gflags, colg, (unsigned)(t + 2));   // publish h(t+1)
    }
    // final hidden state -> d_out hn region (fp32)
    #pragma unroll
    for (int p = 0; p < 2; ++p)
        #pragma unroll
        for (int i = 0; i < 4; ++i)
            hn_out[(size_t)(grpbase + p * 32 + wm * 16 + quad * 4 + i) * 512 + cb + col_l] = hs[p][i];
}

// ---------------- epilogue: out2 = relu(relu(h)@W3.T + b3); params = out2.Wh[cult] + bh
// hfin = bf16 final h (hbuf0: step 127 wrote buffer (127+1)&1 = 0)
__launch_bounds__(256)
__global__ void k_head(const u16* __restrict__ hfin, const float* __restrict__ W3,
                       const float* __restrict__ b3, const int* __restrict__ cult,
                       const float* __restrict__ Wh, const float* __restrict__ bh,
                       float* __restrict__ params) {
    __shared__ float out2[16][264];
    const int tid = threadIdx.x, wave = tid >> 6, lane = tid & 63;
    const int col_l = lane & 15, quad = lane >> 4;
    const int bbase = blockIdx.x * 16;            // 64 blocks x 16 batches

    f32x4 z4 = { 0.f, 0.f, 0.f, 0.f };
    f32x4 acc[4];
    #pragma unroll
    for (int nt = 0; nt < 4; ++nt) acc[nt] = z4;

    #pragma unroll
    for (int kc = 0; kc < 16; ++kc) {
        short8 a = *(const short8*)(hfin + (size_t)(bbase + col_l) * 512 + kc * 32 + quad * 8);
        #pragma unroll
        for (int e = 0; e < 8; ++e) {             // relu on packed bf16 (sign test)
            u16 v = (u16)a[e];
            a[e] = (short)((v & 0x8000u) ? 0 : v);
        }
        #pragma unroll
        for (int nt = 0; nt < 4; ++nt) {
            int nrow = wave * 64 + nt * 16 + col_l;
            const float* wr = W3 + (size_t)nrow * 512 + kc * 32 + quad * 8;
            short8 b;
            #pragma unroll
            for (int e = 0; e < 8; ++e) b[e] = (short)f2bf(wr[e]);
            acc[nt] = mfma16(a, b, acc[nt]);
        }
    }
    #pragma unroll
    for (int nt = 0; nt < 4; ++nt) {
        int ncol = wave * 64 + nt * 16 + col_l;
        float bias = b3[ncol];
        #pragma unroll
        for (int i = 0; i < 4; ++i) {
            float v = acc[nt][i] + bias;
            out2[quad * 4 + i][ncol] = v > 0.f ? v : 0.f;
        }
    }
    __syncthreads();
    // per-cultivar head: 16 batches x 16 outputs = 256 threads, 256-MAC dot each
    int b_local = tid >> 4, o2 = tid & 15;
    int batch = bbase + b_local;
    int c = cult[batch];
    float acc2 = bh[c * 16 + o2];
    const float* wrow = Wh + (size_t)(c * 16 + o2) * 256;
    for (int d = 0; d < 256; ++d) acc2 += out2[b_local][d] * wrow[d];
    params[(size_t)batch * 16 + o2] = acc2;
}

// ---------------- launcher ----------------
extern "C" void kernel_launch(void* const* d_in, const int* in_sizes, int n_in,
                              void* d_out, int out_size, void* d_ws, size_t ws_size,
                              hipStream_t stream) {
    (void)in_sizes; (void)n_in; (void)out_size; (void)ws_size;
    const float* input = (const float*)d_in[0];
    const float* hn    = (const float*)d_in[1];
    const int*   cult  = (const int*)d_in[2];
    const float* W1    = (const float*)d_in[3];
    const float* b1    = (const float*)d_in[4];
    const float* W2    = (const float*)d_in[5];
    const float* b2    = (const float*)d_in[6];
    const float* W_ih  = (const float*)d_in[7];
    const float* W_hh  = (const float*)d_in[8];
    const float* b_ih  = (const float*)d_in[9];
    const float* b_hh  = (const float*)d_in[10];
    const float* W3    = (const float*)d_in[11];
    const float* b3    = (const float*)d_in[12];
    const float* Wh    = (const float*)d_in[13];
    const float* bh    = (const float*)d_in[14];

    char* ws = (char*)d_ws;
    u16*      hbuf0 = (u16*)(ws + WS_HBUF0);
    u16*      hbuf1 = (u16*)(ws + WS_HBUF1);
    float*    W21   = (float*)(ws + WS_W21);
    float*    b21   = (float*)(ws + WS_B21);
    u16*      Weff  = (u16*)(ws + WS_WEFF);
    float*    beff  = (float*)(ws + WS_BEFF);
    unsigned* flags = (unsigned*)(ws + WS_FLAGS);

    float* out    = (float*)d_out;
    float* params = out;            // 1024*16 fp32
    float* hnout  = out + 16384;    // 1024*512 fp32

    // opt in to 132KB dynamic LDS (gfx950: 160KB/CU). Idempotent host call.
    hipFuncSetAttribute((const void*)k_gru,
                        hipFuncAttributeMaxDynamicSharedMemorySize, LDS_BYTES);

    k_prep0<<<64, 256, 0, stream>>>(W1, b1, W2, b2, W21, b21, flags);
    k_prep1<<<192, 256, 0, stream>>>(W_ih, b_ih, W21, b21, Weff, beff);
    k_gru<<<256, 256, LDS_BYTES, stream>>>(input, hn, W_hh, b_hh, Weff, beff,
                                           hbuf0, hbuf1, flags, hnout);
    k_head<<<64, 256, 0, stream>>>(hbuf0, W3, b3, cult, Wh, bh, params);
}

// Round 6
// 809.255 us; speedup vs baseline: 7.3559x; 1.1596x over previous
//
#include <hip/hip_runtime.h>

// ---------------------------------------------------------------------------
// FCGRU (fp32 globals; bf16 in MFMA frags):
//   input(1024,128,32) -> FC(32->256) -> FC(256->512) -> GRU(512) over T=128
//   -> relu -> FC(512->256)+relu -> per-cultivar head (256->16)
// Input-side linears collapse: gx = input @ (W_ih@W2@W1).T + b_eff  (K=32 MFMA).
// Persistent GRU: 16 groups x 16 col-blocks. Cross-block h via sc1 (relaxed
// agent atomics, MALL-coherent). Per step each block stages its group's h slab
// (64 rows x 1KB) into LDS with coalesced sc1 loads (single phase, one sync).
// W_hh B-frags are REGISTER-RESIDENT (48 short8/wave, step-invariant; unified
// VGPR/AGPR file) -- LDS carries only the h slab. Flag barrier (no RMW).
// ---------------------------------------------------------------------------

#define T_STEPS 128
#define PITCH   516             // u16 row pitch in LDS: 258 dw, b64 reads ~conflict-free
#define SLAB_ROWS 64
#define LDS_BYTES (SLAB_ROWS * PITCH * 2)   // 66,048 B

typedef __attribute__((ext_vector_type(8))) short short8;
typedef __attribute__((ext_vector_type(4))) float f32x4;
typedef __attribute__((ext_vector_type(4))) float float4v;
typedef unsigned short u16;
typedef unsigned long long u64;

static __device__ __forceinline__ u16 f2bf(float f) {
    unsigned int u = __builtin_bit_cast(unsigned int, f);
    u += 0x7FFFu + ((u >> 16) & 1u);          // round-to-nearest-even
    return (u16)(u >> 16);
}
static __device__ __forceinline__ f32x4 mfma16(short8 a, short8 b, f32x4 c) {
    return __builtin_amdgcn_mfma_f32_16x16x32_bf16(a, b, c, 0, 0, 0);
}
// device-coherent (MALL) accesses: relaxed agent atomics -> plain sc1 ld/st
static __device__ __forceinline__ void st_h16(u16* p, short8 v) {
    struct W { u64 a, b; } w = __builtin_bit_cast(W, v);
    u64* q = (u64*)p;
    __hip_atomic_store(q + 0, w.a, __ATOMIC_RELAXED, __HIP_MEMORY_SCOPE_AGENT);
    __hip_atomic_store(q + 1, w.b, __ATOMIC_RELAXED, __HIP_MEMORY_SCOPE_AGENT);
}
static __device__ __forceinline__ u64 ld_sc1_u64(const u16* p) {
    return __hip_atomic_load((const u64*)p, __ATOMIC_RELAXED, __HIP_MEMORY_SCOPE_AGENT);
}
// 16B LDS fragment read as two b64 (8B-aligned)
static __device__ __forceinline__ short8 lds8(const u16* p) {
    u64 lo = *(const u64*)p;
    u64 hi = *(const u64*)(p + 4);
    struct W { u64 a, b; } w{lo, hi};
    return __builtin_bit_cast(short8, w);
}

// ---------------- workspace layout (bytes) ----------------
#define WS_HBUF0 0           // 1024*512*2 bf16 h buffer 0
#define WS_HBUF1 1048576     // 1024*512*2 bf16 h buffer 1
#define WS_W21   2097152     // 512*32*4 fp32 W2@W1
#define WS_B21   2162688     // 512*4
#define WS_WEFF  2164736     // 1536*32*2 bf16 W_ih@W2@W1
#define WS_BEFF  2263040     // 1536*4
#define WS_FLAGS 2269184     // 16 groups x 32 slots x 4B = 2048

// ---------------- prologue 0: W21 = W2@W1 (fp32); b21 = W2@b1 + b2; zero flags
__global__ void k_prep0(const float* __restrict__ W1, const float* __restrict__ b1,
                        const float* __restrict__ W2, const float* __restrict__ b2,
                        float* __restrict__ W21, float* __restrict__ b21,
                        unsigned* __restrict__ flags) {
    if (blockIdx.x == 0) {
        __hip_atomic_store(&flags[threadIdx.x], 0u, __ATOMIC_RELAXED, __HIP_MEMORY_SCOPE_AGENT);
        __hip_atomic_store(&flags[256 + threadIdx.x], 0u, __ATOMIC_RELAXED, __HIP_MEMORY_SCOPE_AGENT);
    }
    int gid = blockIdx.x * 256 + threadIdx.x;   // 64 blocks: 512*32 outputs
    int k = gid >> 5, d = gid & 31;
    float acc = 0.f;
    for (int j = 0; j < 256; ++j)
        acc += W2[k * 256 + j] * W1[j * 32 + d];
    W21[k * 32 + d] = acc;
    if (d == 0) {
        float bb = b2[k];
        for (int j = 0; j < 256; ++j) bb += W2[k * 256 + j] * b1[j];
        b21[k] = bb;
    }
}

// ---------------- prologue 1: Weff = bf16(W_ih@W21); beff = W_ih@b21 + b_ih
__global__ void k_prep1(const float* __restrict__ W_ih, const float* __restrict__ b_ih,
                        const float* __restrict__ W21, const float* __restrict__ b21,
                        u16* __restrict__ Weff, float* __restrict__ beff) {
    int gid = blockIdx.x * 256 + threadIdx.x;   // 192 blocks: 1536*32 outputs
    int g = gid >> 5, d = gid & 31;
    float acc = 0.f;
    for (int k = 0; k < 512; ++k)
        acc += W_ih[g * 512 + k] * W21[k * 32 + d];
    Weff[g * 32 + d] = f2bf(acc);
    if (d == 0) {
        float bb = b_ih[g];
        for (int k = 0; k < 512; ++k) bb += W_ih[g * 512 + k] * b21[k];
        beff[g] = bb;
    }
}

// ---------------- flag barrier (no RMW) ----------------
static __device__ __forceinline__ void bar_arrive(unsigned* gflags, int slot, unsigned v) {
    __syncthreads();      // drains vmcnt(0): all waves' sc1 h-stores at MALL
    if (threadIdx.x == 0)
        __hip_atomic_store(&gflags[slot], v, __ATOMIC_RELAXED, __HIP_MEMORY_SCOPE_AGENT);
}
static __device__ __forceinline__ void bar_wait(const unsigned* gflags, unsigned v) {
    if (threadIdx.x < 64) {
        int idx = threadIdx.x & 15;
        for (;;) {
            unsigned f = __hip_atomic_load(&gflags[idx], __ATOMIC_RELAXED, __HIP_MEMORY_SCOPE_AGENT);
            if (__ballot(f >= v) == ~0ull) break;
            __builtin_amdgcn_s_sleep(1);
        }
    }
    __syncthreads();
}

// ---------------- GRU persistent kernel ----------------
// grid 256 x 256. grp = blk&15 (64 batches), colg = blk>>4 (32 h-cols).
// wave: wcol = wave&1 (16-col tile), wm = wave>>1; each wave does m-tiles
// {wm*2, wm*2+1} (16 rows each) reusing its register-resident B-frags.
__launch_bounds__(256, 1)
__global__ void k_gru(const float* __restrict__ input, const float* __restrict__ hn,
                      const float* __restrict__ W_hh, const float* __restrict__ b_hh,
                      const u16* __restrict__ Weff, const float* __restrict__ beff,
                      u16* __restrict__ hbuf0, u16* __restrict__ hbuf1,
                      unsigned* __restrict__ flags, float* __restrict__ hn_out) {
    extern __shared__ __align__(16) u16 slab[];   // [64][PITCH] bf16 h slab

    const int tid  = threadIdx.x;
    const int wave = tid >> 6, lane = tid & 63;
    const int col_l = lane & 15, quad = lane >> 4;
    const int blk = blockIdx.x;
    const int grp = blk & 15, colg = blk >> 4;
    const int colbase = colg * 32;
    const int grpbase = grp * 64;
    const int wcol = wave & 1, wm = wave >> 1;
    const int cb = colbase + wcol * 16;         // wave's 16-col tile base
    unsigned* gflags = flags + grp * 32;

    // copy this block's 4 rows of hn -> hbuf0 (bf16, sc1, own group's rows)
    {
        int b = grpbase + colg * 4 + wave;       // 1 row per wave
        const float* src = hn + (size_t)b * 512 + lane * 8;
        short8 v;
        #pragma unroll
        for (int e = 0; e < 8; ++e) v[e] = (short)f2bf(src[e]);
        st_h16(hbuf0 + (size_t)b * 512 + lane * 8, v);
    }
    // register-resident W_hh B-frags: 3 gates x 16 kc (step-invariant).
    // frag layout for 16x16x32: B[n=col_l][k=quad*8+e] at row g3*512+cb+col_l.
    short8 whhf[3][16];
    #pragma unroll
    for (int g3 = 0; g3 < 3; ++g3) {
        const float* wrow = W_hh + (size_t)(g3 * 512 + cb + col_l) * 512;
        #pragma unroll
        for (int kc = 0; kc < 16; ++kc) {
            const float* p = wrow + kc * 32 + quad * 8;
            short8 v;
            #pragma unroll
            for (int e = 0; e < 8; ++e) v[e] = (short)f2bf(p[e]);
            whhf[g3][kc] = v;
        }
    }
    // register-resident W_eff B-frags (bf16) + per-column biases (fp32)
    short8 bwx[3];
    float bx[3], bhh[3];
    #pragma unroll
    for (int g3 = 0; g3 < 3; ++g3) {
        int nr = g3 * 512 + cb + col_l;
        bwx[g3] = *(const short8*)(Weff + nr * 32 + quad * 8);
        bx[g3]  = beff[nr];
        bhh[g3] = b_hh[nr];
    }
    // fp32 carried h-state: batch = grpbase + (wm*2+m)*16 + quad*4 + i, col cb+col_l
    float hs[2][4];
    #pragma unroll
    for (int m = 0; m < 2; ++m)
        #pragma unroll
        for (int i = 0; i < 4; ++i)
            hs[m][i] = hn[(size_t)(grpbase + (wm * 2 + m) * 16 + quad * 4 + i) * 512 + cb + col_l];

    bar_arrive(gflags, colg, 1u);                 // hn staging published

    u16* bufs[2] = { hbuf0, hbuf1 };
    #pragma unroll 1
    for (int t = 0; t < T_STEPS; ++t) {
        const u16* hsrc = bufs[t & 1];
        u16* hdst = bufs[(t + 1) & 1];

        // x loads for both m-tiles (cached, h-independent; overlap the wait)
        float xf[2][8];
        #pragma unroll
        for (int m = 0; m < 2; ++m) {
            const float* xp = input + (size_t)(grpbase + (wm * 2 + m) * 16 + col_l) * 4096 + t * 32 + quad * 8;
            float4v a = *(const float4v*)xp;
            float4v b = *(const float4v*)(xp + 4);
            #pragma unroll
            for (int e = 0; e < 4; ++e) { xf[m][e] = a[e]; xf[m][4 + e] = b[e]; }
        }

        bar_wait(gflags, (unsigned)(t + 1));      // h(t) visible group-wide

        // stage the whole 64-row slab coalesced (lane-contiguous sc1), 1 sync
        {
            u64 stg[32];
            #pragma unroll
            for (int r16 = 0; r16 < 16; ++r16)
                #pragma unroll
                for (int j = 0; j < 2; ++j)
                    stg[r16 * 2 + j] = ld_sc1_u64(hsrc + (size_t)(grpbase + wave * 16 + r16) * 512 + j * 256 + lane * 4);
            #pragma unroll
            for (int r16 = 0; r16 < 16; ++r16)
                #pragma unroll
                for (int j = 0; j < 2; ++j)
                    *(u64*)&slab[(wave * 16 + r16) * PITCH + j * 256 + lane * 4] = stg[r16 * 2 + j];
        }
        __syncthreads();                          // slab ready

        // ---- compute both m-tiles, reusing register B-frags ----
        #pragma unroll
        for (int m = 0; m < 2; ++m) {
            // gx seed (K=32 MFMA; x fp32 -> bf16)
            short8 ax;
            #pragma unroll
            for (int e = 0; e < 8; ++e) ax[e] = (short)f2bf(xf[m][e]);
            f32x4 z4 = { 0.f, 0.f, 0.f, 0.f };
            f32x4 ar  = mfma16(ax, bwx[0], z4);
            f32x4 az  = mfma16(ax, bwx[1], z4);
            f32x4 anx = mfma16(ax, bwx[2], z4);
            f32x4 anh = z4;
            // gh: K=512, A from slab, B from registers
            const int arow = ((wm * 2 + m) * 16 + col_l) * PITCH;
            #pragma unroll
            for (int kc = 0; kc < 16; ++kc) {
                short8 a = lds8(slab + arow + kc * 32 + quad * 8);
                ar  = mfma16(a, whhf[0][kc], ar);
                az  = mfma16(a, whhf[1][kc], az);
                anh = mfma16(a, whhf[2][kc], anh);
            }
            // gates + state update (fp32), sc1 bf16 h_new stores
            #pragma unroll
            for (int i = 0; i < 4; ++i) {
                float r = 1.f / (1.f + __expf(-(ar[i] + bx[0] + bhh[0])));
                float z = 1.f / (1.f + __expf(-(az[i] + bx[1] + bhh[1])));
                float np = anx[i] + bx[2] + r * (anh[i] + bhh[2]);
                float e  = __expf(-2.f * fabsf(np));
                float nn = __builtin_copysignf((1.f - e) / (1.f + e), np);
                float h  = (1.f - z) * nn + z * hs[m][i];
                hs[m][i] = h;
                int b = grpbase + (wm * 2 + m) * 16 + quad * 4 + i;
                __hip_atomic_store(&hdst[(size_t)b * 512 + cb + col_l], f2bf(h),
                                   __ATOMIC_RELAXED, __HIP_MEMORY_SCOPE_AGENT);
            }
        }
        bar_arrive(gflags, colg, (unsigned)(t + 2));   // publish h(t+1)
    }
    // final hidden state -> d_out hn region (fp32)
    #pragma unroll
    for (int m = 0; m < 2; ++m)
        #pragma unroll
        for (int i = 0; i < 4; ++i)
            hn_out[(size_t)(grpbase + (wm * 2 + m) * 16 + quad * 4 + i) * 512 + cb + col_l] = hs[m][i];
}

// ---------------- epilogue: out2 = relu(relu(h)@W3.T + b3); params = out2.Wh[cult] + bh
// hfin = bf16 final h (hbuf0: step 127 wrote buffer (127+1)&1 = 0)
__launch_bounds__(256)
__global__ void k_head(const u16* __restrict__ hfin, const float* __restrict__ W3,
                       const float* __restrict__ b3, const int* __restrict__ cult,
                       const float* __restrict__ Wh, const float* __restrict__ bh,
                       float* __restrict__ params) {
    __shared__ float out2[16][264];
    const int tid = threadIdx.x, wave = tid >> 6, lane = tid & 63;
    const int col_l = lane & 15, quad = lane >> 4;
    const int bbase = blockIdx.x * 16;            // 64 blocks x 16 batches

    f32x4 z4 = { 0.f, 0.f, 0.f, 0.f };
    f32x4 acc[4];
    #pragma unroll
    for (int nt = 0; nt < 4; ++nt) acc[nt] = z4;

    #pragma unroll
    for (int kc = 0; kc < 16; ++kc) {
        short8 a = *(const short8*)(hfin + (size_t)(bbase + col_l) * 512 + kc * 32 + quad * 8);
        #pragma unroll
        for (int e = 0; e < 8; ++e) {             // relu on packed bf16 (sign test)
            u16 v = (u16)a[e];
            a[e] = (short)((v & 0x8000u) ? 0 : v);
        }
        #pragma unroll
        for (int nt = 0; nt < 4; ++nt) {
            int nrow = wave * 64 + nt * 16 + col_l;
            const float* wr = W3 + (size_t)nrow * 512 + kc * 32 + quad * 8;
            short8 b;
            #pragma unroll
            for (int e = 0; e < 8; ++e) b[e] = (short)f2bf(wr[e]);
            acc[nt] = mfma16(a, b, acc[nt]);
        }
    }
    #pragma unroll
    for (int nt = 0; nt < 4; ++nt) {
        int ncol = wave * 64 + nt * 16 + col_l;
        float bias = b3[ncol];
        #pragma unroll
        for (int i = 0; i < 4; ++i) {
            float v = acc[nt][i] + bias;
            out2[quad * 4 + i][ncol] = v > 0.f ? v : 0.f;
        }
    }
    __syncthreads();
    // per-cultivar head: 16 batches x 16 outputs = 256 threads, 256-MAC dot each
    int b_local = tid >> 4, o2 = tid & 15;
    int batch = bbase + b_local;
    int c = cult[batch];
    float acc2 = bh[c * 16 + o2];
    const float* wrow = Wh + (size_t)(c * 16 + o2) * 256;
    for (int d = 0; d < 256; ++d) acc2 += out2[b_local][d] * wrow[d];
    params[(size_t)batch * 16 + o2] = acc2;
}

// ---------------- launcher ----------------
extern "C" void kernel_launch(void* const* d_in, const int* in_sizes, int n_in,
                              void* d_out, int out_size, void* d_ws, size_t ws_size,
                              hipStream_t stream) {
    (void)in_sizes; (void)n_in; (void)out_size; (void)ws_size;
    const float* input = (const float*)d_in[0];
    const float* hn    = (const float*)d_in[1];
    const int*   cult  = (const int*)d_in[2];
    const float* W1    = (const float*)d_in[3];
    const float* b1    = (const float*)d_in[4];
    const float* W2    = (const float*)d_in[5];
    const float* b2    = (const float*)d_in[6];
    const float* W_ih  = (const float*)d_in[7];
    const float* W_hh  = (const float*)d_in[8];
    const float* b_ih  = (const float*)d_in[9];
    const float* b_hh  = (const float*)d_in[10];
    const float* W3    = (const float*)d_in[11];
    const float* b3    = (const float*)d_in[12];
    const float* Wh    = (const float*)d_in[13];
    const float* bh    = (const float*)d_in[14];

    char* ws = (char*)d_ws;
    u16*      hbuf0 = (u16*)(ws + WS_HBUF0);
    u16*      hbuf1 = (u16*)(ws + WS_HBUF1);
    float*    W21   = (float*)(ws + WS_W21);
    float*    b21   = (float*)(ws + WS_B21);
    u16*      Weff  = (u16*)(ws + WS_WEFF);
    float*    beff  = (float*)(ws + WS_BEFF);
    unsigned* flags = (unsigned*)(ws + WS_FLAGS);

    float* out    = (float*)d_out;
    float* params = out;            // 1024*16 fp32
    float* hnout  = out + 16384;    // 1024*512 fp32

    hipFuncSetAttribute((const void*)k_gru,
                        hipFuncAttributeMaxDynamicSharedMemorySize, LDS_BYTES);

    k_prep0<<<64, 256, 0, stream>>>(W1, b1, W2, b2, W21, b21, flags);
    k_prep1<<<192, 256, 0, stream>>>(W_ih, b_ih, W21, b21, Weff, beff);
    k_gru<<<256, 256, LDS_BYTES, stream>>>(input, hn, W_hh, b_hh, Weff, beff,
                                           hbuf0, hbuf1, flags, hnout);
    k_head<<<64, 256, 0, stream>>>(hbuf0, W3, b3, cult, Wh, bh, params);
}

// Round 7
// 741.776 us; speedup vs baseline: 8.0251x; 1.0910x over previous
//
#include <hip/hip_runtime.h>

// ---------------------------------------------------------------------------
// FCGRU (fp32 globals; bf16 in MFMA frags):
//   input(1024,128,32) -> FC(32->256) -> FC(256->512) -> GRU(512) over T=128
//   -> relu -> FC(512->256)+relu -> per-cultivar head (256->16)
// Input-side linears collapse: gx = input @ (W_ih@W2@W1).T + b_eff  (K=32 MFMA).
// Persistent GRU: 32 groups x 8 col-blocks (32 batches/group, 64 cols/block).
// Cross-block h via sc1 (relaxed agent atomics, MALL-coherent) -- measured
// ~3 TB/s ceiling, so traffic halved vs r6: 8 MB/step. W_hh B-frags register-
// resident (48 short8/wave). 33KB static LDS h slab, coalesced sc1 staging
// with colg-rotated row order. 8-flag barrier (single line, no RMW).
// ---------------------------------------------------------------------------

#define T_STEPS 128
#define PITCH   516             // u16 row pitch in LDS: b64 frag reads ~conflict-free
#define SLAB_ROWS 32

typedef __attribute__((ext_vector_type(8))) short short8;
typedef __attribute__((ext_vector_type(4))) float f32x4;
typedef __attribute__((ext_vector_type(4))) float float4v;
typedef unsigned short u16;
typedef unsigned long long u64;

static __device__ __forceinline__ u16 f2bf(float f) {
    unsigned int u = __builtin_bit_cast(unsigned int, f);
    u += 0x7FFFu + ((u >> 16) & 1u);          // round-to-nearest-even
    return (u16)(u >> 16);
}
static __device__ __forceinline__ f32x4 mfma16(short8 a, short8 b, f32x4 c) {
    return __builtin_amdgcn_mfma_f32_16x16x32_bf16(a, b, c, 0, 0, 0);
}
// device-coherent (MALL) accesses: relaxed agent atomics -> plain sc1 ld/st
static __device__ __forceinline__ void st_h16(u16* p, short8 v) {
    struct W { u64 a, b; } w = __builtin_bit_cast(W, v);
    u64* q = (u64*)p;
    __hip_atomic_store(q + 0, w.a, __ATOMIC_RELAXED, __HIP_MEMORY_SCOPE_AGENT);
    __hip_atomic_store(q + 1, w.b, __ATOMIC_RELAXED, __HIP_MEMORY_SCOPE_AGENT);
}
static __device__ __forceinline__ u64 ld_sc1_u64(const u16* p) {
    return __hip_atomic_load((const u64*)p, __ATOMIC_RELAXED, __HIP_MEMORY_SCOPE_AGENT);
}
// 16B LDS fragment read as two b64 (8B-aligned)
static __device__ __forceinline__ short8 lds8(const u16* p) {
    u64 lo = *(const u64*)p;
    u64 hi = *(const u64*)(p + 4);
    struct W { u64 a, b; } w{lo, hi};
    return __builtin_bit_cast(short8, w);
}

// ---------------- workspace layout (bytes) ----------------
#define WS_HBUF0 0           // 1024*512*2 bf16 h buffer 0
#define WS_HBUF1 1048576     // 1024*512*2 bf16 h buffer 1
#define WS_W21   2097152     // 512*32*4 fp32 W2@W1
#define WS_B21   2162688     // 512*4
#define WS_WEFF  2164736     // 1536*32*2 bf16 W_ih@W2@W1
#define WS_BEFF  2263040     // 1536*4
#define WS_FLAGS 2269184     // 32 groups x 8 slots x 4B = 1024

// ---------------- prologue 0: W21 = W2@W1 (fp32); b21 = W2@b1 + b2; zero flags
__global__ void k_prep0(const float* __restrict__ W1, const float* __restrict__ b1,
                        const float* __restrict__ W2, const float* __restrict__ b2,
                        float* __restrict__ W21, float* __restrict__ b21,
                        unsigned* __restrict__ flags) {
    if (blockIdx.x == 0)
        __hip_atomic_store(&flags[threadIdx.x], 0u, __ATOMIC_RELAXED, __HIP_MEMORY_SCOPE_AGENT);
    int gid = blockIdx.x * 256 + threadIdx.x;   // 64 blocks: 512*32 outputs
    int k = gid >> 5, d = gid & 31;
    float acc = 0.f;
    for (int j = 0; j < 256; ++j)
        acc += W2[k * 256 + j] * W1[j * 32 + d];
    W21[k * 32 + d] = acc;
    if (d == 0) {
        float bb = b2[k];
        for (int j = 0; j < 256; ++j) bb += W2[k * 256 + j] * b1[j];
        b21[k] = bb;
    }
}

// ---------------- prologue 1: Weff = bf16(W_ih@W21); beff = W_ih@b21 + b_ih
__global__ void k_prep1(const float* __restrict__ W_ih, const float* __restrict__ b_ih,
                        const float* __restrict__ W21, const float* __restrict__ b21,
                        u16* __restrict__ Weff, float* __restrict__ beff) {
    int gid = blockIdx.x * 256 + threadIdx.x;   // 192 blocks: 1536*32 outputs
    int g = gid >> 5, d = gid & 31;
    float acc = 0.f;
    for (int k = 0; k < 512; ++k)
        acc += W_ih[g * 512 + k] * W21[k * 32 + d];
    Weff[g * 32 + d] = f2bf(acc);
    if (d == 0) {
        float bb = b_ih[g];
        for (int k = 0; k < 512; ++k) bb += W_ih[g * 512 + k] * b21[k];
        beff[g] = bb;
    }
}

// ---------------- flag barrier (no RMW) ----------------
static __device__ __forceinline__ void bar_arrive(unsigned* gflags, int slot, unsigned v) {
    __syncthreads();      // drains vmcnt(0): all waves' sc1 h-stores at MALL
    if (threadIdx.x == 0)
        __hip_atomic_store(&gflags[slot], v, __ATOMIC_RELAXED, __HIP_MEMORY_SCOPE_AGENT);
}
static __device__ __forceinline__ void bar_wait(const unsigned* gflags, unsigned v) {
    if (threadIdx.x < 64) {
        int idx = threadIdx.x & 7;               // 8 flags, one 32B span
        for (;;) {
            unsigned f = __hip_atomic_load(&gflags[idx], __ATOMIC_RELAXED, __HIP_MEMORY_SCOPE_AGENT);
            if (__ballot(f >= v) == ~0ull) break;
            __builtin_amdgcn_s_sleep(1);
        }
    }
    __syncthreads();
}

// ---------------- GRU persistent kernel ----------------
// grid 256 x 256. grp = blk&31 (32 batches), colg = blk>>5 (64 h-cols).
// wave w owns col-tile cb = colg*64 + w*16 and computes both 16-row m-tiles.
__launch_bounds__(256, 1)
__global__ void k_gru(const float* __restrict__ input, const float* __restrict__ hn,
                      const float* __restrict__ W_hh, const float* __restrict__ b_hh,
                      const u16* __restrict__ Weff, const float* __restrict__ beff,
                      u16* __restrict__ hbuf0, u16* __restrict__ hbuf1,
                      unsigned* __restrict__ flags, float* __restrict__ hn_out) {
    __shared__ __align__(16) u16 slab[SLAB_ROWS * PITCH];   // 33 KB h slab

    const int tid  = threadIdx.x;
    const int wave = tid >> 6, lane = tid & 63;
    const int col_l = lane & 15, quad = lane >> 4;
    const int blk = blockIdx.x;
    const int grp = blk & 31, colg = blk >> 5;
    const int grpbase = grp * 32;               // group's 32 batches
    const int cb = colg * 64 + wave * 16;       // wave's 16-col tile base
    unsigned* gflags = flags + grp * 8;

    // copy this block's 4 rows of hn -> hbuf0 (bf16, sc1, own group's rows)
    {
        int b = grpbase + colg * 4 + wave;       // 8 blocks x 4 rows = 32 ✓
        const float* src = hn + (size_t)b * 512 + lane * 8;
        short8 v;
        #pragma unroll
        for (int e = 0; e < 8; ++e) v[e] = (short)f2bf(src[e]);
        st_h16(hbuf0 + (size_t)b * 512 + lane * 8, v);
    }
    // register-resident W_hh B-frags: 3 gates x 16 kc (step-invariant)
    short8 whhf[3][16];
    #pragma unroll
    for (int g3 = 0; g3 < 3; ++g3) {
        const float* wrow = W_hh + (size_t)(g3 * 512 + cb + col_l) * 512;
        #pragma unroll
        for (int kc = 0; kc < 16; ++kc) {
            const float* p = wrow + kc * 32 + quad * 8;
            short8 v;
            #pragma unroll
            for (int e = 0; e < 8; ++e) v[e] = (short)f2bf(p[e]);
            whhf[g3][kc] = v;
        }
    }
    // register-resident W_eff B-frags (bf16) + per-column biases (fp32)
    short8 bwx[3];
    float bx[3], bhh[3];
    #pragma unroll
    for (int g3 = 0; g3 < 3; ++g3) {
        int nr = g3 * 512 + cb + col_l;
        bwx[g3] = *(const short8*)(Weff + nr * 32 + quad * 8);
        bx[g3]  = beff[nr];
        bhh[g3] = b_hh[nr];
    }
    // fp32 carried h-state: batch = grpbase + m*16 + quad*4 + i, col cb+col_l
    float hs[2][4];
    #pragma unroll
    for (int m = 0; m < 2; ++m)
        #pragma unroll
        for (int i = 0; i < 4; ++i)
            hs[m][i] = hn[(size_t)(grpbase + m * 16 + quad * 4 + i) * 512 + cb + col_l];

    bar_arrive(gflags, colg, 1u);                 // hn staging published

    u16* bufs[2] = { hbuf0, hbuf1 };
    #pragma unroll 1
    for (int t = 0; t < T_STEPS; ++t) {
        const u16* hsrc = bufs[t & 1];
        u16* hdst = bufs[(t + 1) & 1];

        // x loads for both m-tiles (cached, h-independent; overlap the wait)
        float xf[2][8];
        #pragma unroll
        for (int m = 0; m < 2; ++m) {
            const float* xp = input + (size_t)(grpbase + m * 16 + col_l) * 4096 + t * 32 + quad * 8;
            float4v a = *(const float4v*)xp;
            float4v b = *(const float4v*)(xp + 4);
            #pragma unroll
            for (int e = 0; e < 4; ++e) { xf[m][e] = a[e]; xf[m][4 + e] = b[e]; }
        }

        bar_wait(gflags, (unsigned)(t + 1));      // h(t) visible group-wide

        // stage the 32-row slab coalesced (lane-contiguous sc1), rows rotated
        // by colg so the 8 blocks of a group don't hit identical MALL lines
        {
            u64 stg[16];
            #pragma unroll
            for (int r8 = 0; r8 < 8; ++r8) {
                int r = (wave * 8 + r8 + colg * 4) & 31;
                #pragma unroll
                for (int j = 0; j < 2; ++j)
                    stg[r8 * 2 + j] = ld_sc1_u64(hsrc + (size_t)(grpbase + r) * 512 + j * 256 + lane * 4);
            }
            #pragma unroll
            for (int r8 = 0; r8 < 8; ++r8) {
                int r = (wave * 8 + r8 + colg * 4) & 31;
                #pragma unroll
                for (int j = 0; j < 2; ++j)
                    *(u64*)&slab[r * PITCH + j * 256 + lane * 4] = stg[r8 * 2 + j];
            }
        }
        __syncthreads();                          // slab ready

        // ---- compute both m-tiles, reusing register B-frags ----
        #pragma unroll
        for (int m = 0; m < 2; ++m) {
            // gx seed (K=32 MFMA; x fp32 -> bf16)
            short8 ax;
            #pragma unroll
            for (int e = 0; e < 8; ++e) ax[e] = (short)f2bf(xf[m][e]);
            f32x4 z4 = { 0.f, 0.f, 0.f, 0.f };
            f32x4 ar  = mfma16(ax, bwx[0], z4);
            f32x4 az  = mfma16(ax, bwx[1], z4);
            f32x4 anx = mfma16(ax, bwx[2], z4);
            f32x4 anh = z4;
            // gh: K=512, A from slab, B from registers
            const int arow = (m * 16 + col_l) * PITCH;
            #pragma unroll
            for (int kc = 0; kc < 16; ++kc) {
                short8 a = lds8(slab + arow + kc * 32 + quad * 8);
                ar  = mfma16(a, whhf[0][kc], ar);
                az  = mfma16(a, whhf[1][kc], az);
                anh = mfma16(a, whhf[2][kc], anh);
            }
            // gates + state update (fp32), sc1 bf16 h_new stores
            #pragma unroll
            for (int i = 0; i < 4; ++i) {
                float r = 1.f / (1.f + __expf(-(ar[i] + bx[0] + bhh[0])));
                float z = 1.f / (1.f + __expf(-(az[i] + bx[1] + bhh[1])));
                float np = anx[i] + bx[2] + r * (anh[i] + bhh[2]);
                float e  = __expf(-2.f * fabsf(np));
                float nn = __builtin_copysignf((1.f - e) / (1.f + e), np);
                float h  = (1.f - z) * nn + z * hs[m][i];
                hs[m][i] = h;
                int b = grpbase + m * 16 + quad * 4 + i;
                __hip_atomic_store(&hdst[(size_t)b * 512 + cb + col_l], f2bf(h),
                                   __ATOMIC_RELAXED, __HIP_MEMORY_SCOPE_AGENT);
            }
        }
        if (t < T_STEPS - 1)
            bar_arrive(gflags, colg, (unsigned)(t + 2));   // publish h(t+1)
    }
    // final hidden state -> d_out hn region (fp32)
    #pragma unroll
    for (int m = 0; m < 2; ++m)
        #pragma unroll
        for (int i = 0; i < 4; ++i)
            hn_out[(size_t)(grpbase + m * 16 + quad * 4 + i) * 512 + cb + col_l] = hs[m][i];
}

// ---------------- epilogue: out2 = relu(relu(h)@W3.T + b3); params = out2.Wh[cult] + bh
// hfin = bf16 final h (hbuf0: step 127 wrote buffer (127+1)&1 = 0).
// Cache-coherent here: kernel-launch boundary invalidates L1/L2.
__launch_bounds__(256)
__global__ void k_head(const u16* __restrict__ hfin, const float* __restrict__ W3,
                       const float* __restrict__ b3, const int* __restrict__ cult,
                       const float* __restrict__ Wh, const float* __restrict__ bh,
                       float* __restrict__ params) {
    __shared__ float out2[16][264];
    const int tid = threadIdx.x, wave = tid >> 6, lane = tid & 63;
    const int col_l = lane & 15, quad = lane >> 4;
    const int bbase = blockIdx.x * 16;            // 64 blocks x 16 batches

    f32x4 z4 = { 0.f, 0.f, 0.f, 0.f };
    f32x4 acc[4];
    #pragma unroll
    for (int nt = 0; nt < 4; ++nt) acc[nt] = z4;

    #pragma unroll
    for (int kc = 0; kc < 16; ++kc) {
        short8 a = *(const short8*)(hfin + (size_t)(bbase + col_l) * 512 + kc * 32 + quad * 8);
        #pragma unroll
        for (int e = 0; e < 8; ++e) {             // relu on packed bf16 (sign test)
            u16 v = (u16)a[e];
            a[e] = (short)((v & 0x8000u) ? 0 : v);
        }
        #pragma unroll
        for (int nt = 0; nt < 4; ++nt) {
            int nrow = wave * 64 + nt * 16 + col_l;
            const float* wr = W3 + (size_t)nrow * 512 + kc * 32 + quad * 8;
            short8 b;
            #pragma unroll
            for (int e = 0; e < 8; ++e) b[e] = (short)f2bf(wr[e]);
            acc[nt] = mfma16(a, b, acc[nt]);
        }
    }
    #pragma unroll
    for (int nt = 0; nt < 4; ++nt) {
        int ncol = wave * 64 + nt * 16 + col_l;
        float bias = b3[ncol];
        #pragma unroll
        for (int i = 0; i < 4; ++i) {
            float v = acc[nt][i] + bias;
            out2[quad * 4 + i][ncol] = v > 0.f ? v : 0.f;
        }
    }
    __syncthreads();
    // per-cultivar head: 16 batches x 16 outputs = 256 threads, 256-MAC dot each
    int b_local = tid >> 4, o2 = tid & 15;
    int batch = bbase + b_local;
    int c = cult[batch];
    float acc2 = bh[c * 16 + o2];
    const float* wrow = Wh + (size_t)(c * 16 + o2) * 256;
    for (int d = 0; d < 256; ++d) acc2 += out2[b_local][d] * wrow[d];
    params[(size_t)batch * 16 + o2] = acc2;
}

// ---------------- launcher ----------------
extern "C" void kernel_launch(void* const* d_in, const int* in_sizes, int n_in,
                              void* d_out, int out_size, void* d_ws, size_t ws_size,
                              hipStream_t stream) {
    (void)in_sizes; (void)n_in; (void)out_size; (void)ws_size;
    const float* input = (const float*)d_in[0];
    const float* hn    = (const float*)d_in[1];
    const int*   cult  = (const int*)d_in[2];
    const float* W1    = (const float*)d_in[3];
    const float* b1    = (const float*)d_in[4];
    const float* W2    = (const float*)d_in[5];
    const float* b2    = (const float*)d_in[6];
    const float* W_ih  = (const float*)d_in[7];
    const float* W_hh  = (const float*)d_in[8];
    const float* b_ih  = (const float*)d_in[9];
    const float* b_hh  = (const float*)d_in[10];
    const float* W3    = (const float*)d_in[11];
    const float* b3    = (const float*)d_in[12];
    const float* Wh    = (const float*)d_in[13];
    const float* bh    = (const float*)d_in[14];

    char* ws = (char*)d_ws;
    u16*      hbuf0 = (u16*)(ws + WS_HBUF0);
    u16*      hbuf1 = (u16*)(ws + WS_HBUF1);
    float*    W21   = (float*)(ws + WS_W21);
    float*    b21   = (float*)(ws + WS_B21);
    u16*      Weff  = (u16*)(ws + WS_WEFF);
    float*    beff  = (float*)(ws + WS_BEFF);
    unsigned* flags = (unsigned*)(ws + WS_FLAGS);

    float* out    = (float*)d_out;
    float* params = out;            // 1024*16 fp32
    float* hnout  = out + 16384;    // 1024*512 fp32

    k_prep0<<<64, 256, 0, stream>>>(W1, b1, W2, b2, W21, b21, flags);
    k_prep1<<<192, 256, 0, stream>>>(W_ih, b_ih, W21, b21, Weff, beff);
    k_gru<<<256, 256, 0, stream>>>(input, hn, W_hh, b_hh, Weff, beff,
                                   hbuf0, hbuf1, flags, hnout);
    k_head<<<64, 256, 0, stream>>>(hbuf0, W3, b3, cult, Wh, bh, params);
}